// Round 9
// baseline (1320.896 us; speedup 1.0000x reference)
//
#include <hip/hip_runtime.h>
#include <hip/hip_bf16.h>

typedef __hip_bfloat16 bf16;
typedef __attribute__((ext_vector_type(4))) float f32x4;
typedef __attribute__((ext_vector_type(8))) short short8;
typedef __attribute__((ext_vector_type(4))) short short4v;

#define NEGBIG (-3.0e38f)

__device__ __forceinline__ unsigned short f2b(float x) {
  union { float f; unsigned int u; } v; v.f = x;
  unsigned int r = v.u + 0x7fffu + ((v.u >> 16) & 1u);
  return (unsigned short)(r >> 16);
}

__device__ __forceinline__ void gl16(const void* g, void* l) {
  __builtin_amdgcn_global_load_lds(
      (const __attribute__((address_space(1))) unsigned int*)g,
      (__attribute__((address_space(3))) unsigned int*)l, 16, 0, 0);
}

// bijective XCD-grouping swizzle (m204)
__device__ __forceinline__ int xcd_swz(int orig, int nwg) {
  const int q = nwg >> 3, r = nwg & 7;
  const int xcd = orig & 7;
  const int base = (xcd < r) ? xcd * (q + 1) : r * (q + 1) + (xcd - r) * q;
  return base + (orig >> 3);
}

// ---------------- weight f32 -> bf16 (row-major) ----------------
__global__ __launch_bounds__(256) void cvt_w_kernel(
    const float* __restrict__ a, const float* __restrict__ b,
    const float* __restrict__ c, const float* __restrict__ d,
    bf16* __restrict__ dst) {
  const int t = blockIdx.x * 256 + threadIdx.x;
  const float* srcs[4] = {a, b, c, d};
#pragma unroll
  for (int w = 0; w < 4; ++w) {
    const f32x4 v = *(const f32x4*)(srcs[w] + (size_t)t * 4);
    short4v o;
    o[0] = (short)f2b(v[0]); o[1] = (short)f2b(v[1]);
    o[2] = (short)f2b(v[2]); o[3] = (short)f2b(v[3]);
    *(short4v*)((short*)dst + (size_t)w * 262144 + (size_t)t * 4) = o;
  }
}

// ---------------- activation f32 -> bf16 (row-major [M][512]) -------------
__global__ __launch_bounds__(256) void cvt_a(const float* __restrict__ src,
                                             short* __restrict__ dst, int M) {
  const int g = blockIdx.x * 256 + threadIdx.x;
  const int row = g >> 6, k8 = g & 63;
  if (row >= M) return;
  const float* sp = src + (size_t)row * 512 + k8 * 8;
  const f32x4 lo = *(const f32x4*)sp;
  const f32x4 hi = *(const f32x4*)(sp + 4);
  short8 u;
  u[0] = (short)f2b(lo[0]); u[1] = (short)f2b(lo[1]);
  u[2] = (short)f2b(lo[2]); u[3] = (short)f2b(lo[3]);
  u[4] = (short)f2b(hi[0]); u[5] = (short)f2b(hi[1]);
  u[6] = (short)f2b(hi[2]); u[7] = (short)f2b(hi[3]);
  *(short8*)(dst + (size_t)row * 512 + k8 * 8) = u;
}

// ---- bias table -> per-(head, frag-element) layout, pads = NEGBIG ----
__global__ __launch_bounds__(256) void prep_rpbL(const float* __restrict__ btab,
                                                 float* __restrict__ rpbL) {
  const int g = blockIdx.x * 256 + threadIdx.x;
  const int lane = g & 63, mn = (g >> 6) & 15, h = g >> 10;
  const int m = mn >> 2, n = mn & 3, l15 = lane & 15, lg = lane >> 4;
  const int cc = n * 16 + l15;
  const int aj = cc / 7, bj = cc % 7;
  f32x4 o;
#pragma unroll
  for (int reg = 0; reg < 4; ++reg) {
    const int i = m * 16 + lg * 4 + reg;
    if (i < 49 && cc < 49) {
      const int t = (i / 7 - aj + 6) * 13 + (i % 7 - bj + 6);
      o[reg] = btab[t * 16 + h];
    } else {
      o[reg] = NEGBIG;
    }
  }
  ((f32x4*)rpbL)[g] = o;
}

// ---- mask -> per-(window, frag-element) layout, pads = 0 ----
__global__ __launch_bounds__(256) void prep_maskL(const float* __restrict__ mask,
                                                  float* __restrict__ maskL) {
  const int g = blockIdx.x * 256 + threadIdx.x;
  const int lane = g & 63, mn = (g >> 6) & 15, wm = g >> 10;
  const int m = mn >> 2, n = mn & 3, l15 = lane & 15, lg = lane >> 4;
  const int cc = n * 16 + l15;
  f32x4 o;
#pragma unroll
  for (int reg = 0; reg < 4; ++reg) {
    const int i = m * 16 + lg * 4 + reg;
    o[reg] = (i < 49 && cc < 49) ? mask[(size_t)wm * 2401 + i * 49 + cc] : 0.f;
  }
  ((f32x4*)maskL)[g] = o;
}

// ---------------- 8-phase 256x256 GEMM (T2+T3+T4+T5) ------------------------
// MODE 0 (KQV): grid 6*gy; bn%6: cls=bn>>1 (0=K,1=Q,2=V^T), bnl=bn&1.
// MODE 1 (proj): grid 2*gy; f32 out.
// 512 thr / 8 waves (2Mx4N), wave tile 128x64. LDS: 2 buf x (A 32K | B 32K).
// Buffer granularity: 8 units of 8KB (A:u0-3 rows u*64.., B:u0-3). Per phase:
// ds-read one C-quadrant's frags + stage 2 units + 2 barriers. Unit death:
// A-unit 2wr @P1, B-unit wc @P2, A-unit 2wr+1 @P3 -> stage buf0' @P4-P7,
// buf1' @P8,P1',P2',P3'. vmcnt(2) at P4/P8 retires exactly the 8 loads of the
// buffer read next phase; 2 newest stay in flight across the barrier.
template <int MODE>
__global__ __launch_bounds__(512, 2) void gemm8p(
    const short* __restrict__ Al, const short* __restrict__ Ag,
    const short* __restrict__ wbf, const float* __restrict__ bk,
    const float* __restrict__ bq, const float* __restrict__ bv, float qscale,
    bf16* __restrict__ k_ws, bf16* __restrict__ q_ws, bf16* __restrict__ vT_ws,
    float* __restrict__ fout, int M) {
  __shared__ char lds[131072];
  char* buf0 = lds;
  char* buf1 = lds + 65536;
  const int nwg = gridDim.x;
  const int t0 = xcd_swz(blockIdx.x, nwg);
  const int NB = (MODE == 0) ? 6 : 2;
  const int bn = t0 % NB, bm = t0 / NB;
  const int cls = (MODE == 0) ? (bn >> 1) : 3;
  const int bnl = bn & 1;
  const int tid = threadIdx.x, lane = tid & 63, wid = tid >> 6;
  const int l15 = lane & 15, lg = lane >> 4;
  const int wr = wid >> 2, wc = wid & 3;
  const char* Ab = (const char*)((MODE == 1) ? Al : ((cls == 1) ? Ag : Al));
  const char* Bb = (const char*)(wbf + (size_t)((MODE == 1) ? 3 : cls) * 262144);
  const int am0 = bm * 256, bn0 = bnl * 256;
  const bool swap = (MODE == 0) && (cls == 2);
  const int famoff = swap ? 32768 : 0;   // A-operand rows (m-axis)
  const int fbmoff = swap ? 0 : 32768;   // B-operand rows (n-axis)

  const int srow = tid >> 3;                       // 0..63
  const int ssl = ((tid & 7) ^ (srow & 7)) << 4;   // swizzled src slot byte

#define STG_A(dstbuf, u, tk)                                                 \
  gl16(Ab + (size_t)(am0 + (u) * 64 + srow) * 1024 + (tk) * 128 + ssl,       \
       (dstbuf) + (u) * 8192 + tid * 16)
#define STG_B(dstbuf, u, tk)                                                 \
  gl16(Bb + (size_t)(bn0 + (u) * 64 + srow) * 1024 + (tk) * 128 + ssl,       \
       (dstbuf) + 32768 + (u) * 8192 + tid * 16)

  f32x4 acc[8][4];
#pragma unroll
  for (int m = 0; m < 8; ++m)
#pragma unroll
    for (int n = 0; n < 4; ++n) acc[m][n] = (f32x4){0.f, 0.f, 0.f, 0.f};

  short8 af[4][2];
  short8 bfr[2][2][2];  // [set][nj][s]

#define LDA_(cb, mh)                                                         \
  do {                                                                       \
    for (int mi = 0; mi < 4; ++mi)                                           \
      for (int s = 0; s < 2; ++s) {                                          \
        const int r = wr * 128 + ((mh) * 4 + mi) * 16 + l15;                 \
        af[mi][s] = *(const short8*)((cb) + famoff + r * 128 +               \
                                     (((s * 4 + lg) ^ (r & 7)) << 4));       \
      }                                                                      \
  } while (0)
#define LDB_(cb, set, nh)                                                    \
  do {                                                                       \
    for (int nj = 0; nj < 2; ++nj)                                           \
      for (int s = 0; s < 2; ++s) {                                          \
        const int r = wc * 64 + ((nh) * 2 + nj) * 16 + l15;                  \
        bfr[set][nj][s] = *(const short8*)((cb) + fbmoff + r * 128 +         \
                                           (((s * 4 + lg) ^ (r & 7)) << 4)); \
      }                                                                      \
  } while (0)
#define MFMAQ_(mh, nh, set)                                                  \
  do {                                                                       \
    __builtin_amdgcn_s_setprio(1);                                           \
    for (int mi = 0; mi < 4; ++mi)                                           \
      for (int nj = 0; nj < 2; ++nj)                                         \
        for (int s = 0; s < 2; ++s)                                          \
          acc[(mh) * 4 + mi][(nh) * 2 + nj] =                                \
              __builtin_amdgcn_mfma_f32_16x16x32_bf16(                       \
                  af[mi][s], bfr[set][nj][s],                                \
                  acc[(mh) * 4 + mi][(nh) * 2 + nj], 0, 0, 0);               \
    __builtin_amdgcn_s_setprio(0);                                           \
  } while (0)
#define BAR __builtin_amdgcn_s_barrier()
#define LGK0 asm volatile("s_waitcnt lgkmcnt(0)")

  // ---- prologue: tile0 (8 units) + tile1 A-u0,u1; keep 2 in flight
  STG_A(buf0, 0, 0); STG_A(buf0, 1, 0); STG_A(buf0, 2, 0); STG_A(buf0, 3, 0);
  STG_B(buf0, 0, 0); STG_B(buf0, 1, 0); STG_B(buf0, 2, 0); STG_B(buf0, 3, 0);
  STG_A(buf1, 0, 1); STG_A(buf1, 1, 1);
  asm volatile("s_waitcnt vmcnt(2)" ::: "memory");
  BAR;

#pragma unroll 1
  for (int it = 0; it < 4; ++it) {
    const int t1 = 2 * it + 1, t2 = 2 * it + 2, t3 = 2 * it + 3;
    const bool st = (it < 3);
    // P1
    LDA_(buf0, 0); LDB_(buf0, 0, 0);
    STG_A(buf1, 2, t1); STG_A(buf1, 3, t1);
    BAR; LGK0; MFMAQ_(0, 0, 0); BAR;
    // P2
    LDB_(buf0, 1, 1);
    STG_B(buf1, 0, t1); STG_B(buf1, 1, t1);
    BAR; LGK0; MFMAQ_(0, 1, 1); BAR;
    // P3
    LDA_(buf0, 1);
    STG_B(buf1, 2, t1); STG_B(buf1, 3, t1);
    BAR; LGK0; MFMAQ_(1, 0, 0); BAR;
    // P4
    if (st) { STG_A(buf0, 0, t2); STG_A(buf0, 1, t2); }
    BAR; MFMAQ_(1, 1, 1);
    if (st) asm volatile("s_waitcnt vmcnt(2)" ::: "memory");
    else    asm volatile("s_waitcnt vmcnt(0)" ::: "memory");
    BAR;
    // P5
    LDA_(buf1, 0); LDB_(buf1, 0, 0);
    if (st) { STG_A(buf0, 2, t2); STG_A(buf0, 3, t2); }
    BAR; LGK0; MFMAQ_(0, 0, 0); BAR;
    // P6
    LDB_(buf1, 1, 1);
    if (st) { STG_B(buf0, 0, t2); STG_B(buf0, 1, t2); }
    BAR; LGK0; MFMAQ_(0, 1, 1); BAR;
    // P7
    LDA_(buf1, 1);
    if (st) { STG_B(buf0, 2, t2); STG_B(buf0, 3, t2); }
    BAR; LGK0; MFMAQ_(1, 0, 0); BAR;
    // P8
    if (st) { STG_A(buf1, 0, t3); STG_A(buf1, 1, t3); }
    BAR; MFMAQ_(1, 1, 1);
    if (st) asm volatile("s_waitcnt vmcnt(2)" ::: "memory");
    BAR;
  }
#undef STG_A
#undef STG_B
#undef LDA_
#undef LDB_
#undef MFMAQ_
#undef BAR
#undef LGK0

  // ---- epilogues ----
  if (MODE == 1) {
#pragma unroll
    for (int m = 0; m < 8; ++m) {
#pragma unroll
      for (int n = 0; n < 4; ++n) {
        const int c = bn0 + wc * 64 + n * 16 + l15;
        const float bvv = bk[c];  // bk carries bp for MODE 1
#pragma unroll
        for (int reg = 0; reg < 4; ++reg) {
          const int r = am0 + wr * 128 + m * 16 + lg * 4 + reg;
          if (r < M) fout[(size_t)r * 512 + c] = acc[m][n][reg] + bvv;
        }
      }
    }
  } else if (cls == 2) {  // V^T: m-axis = channels, n-axis = tokens
#pragma unroll
    for (int m = 0; m < 8; ++m) {
#pragma unroll
      for (int n = 0; n < 4; ++n) {
        const int tok = am0 + wc * 64 + n * 16 + l15;
        if (tok < M) {
          const int w = tok / 49, nt = tok - w * 49;
#pragma unroll
          for (int reg = 0; reg < 4; ++reg) {
            const int ch = bn0 + wr * 128 + m * 16 + lg * 4 + reg;
            const float v = acc[m][n][reg] + bv[ch];
            const int hh = ch >> 5, dd = ch & 31;
            vT_ws[(((size_t)w * 16 + hh) * 32 + dd) * 64 + nt] =
                __float2bfloat16(v);
          }
        }
      }
    }
  } else {
    const float* bb = (cls == 0) ? bk : bq;
    bf16* dp = (cls == 0) ? k_ws : q_ws;
    const float sc = (cls == 0) ? 1.0f : qscale;
#pragma unroll
    for (int m = 0; m < 8; ++m) {
#pragma unroll
      for (int n = 0; n < 4; ++n) {
        const int c = bn0 + wc * 64 + n * 16 + l15;
        const float bvv = bb[c];
        const int hh = c >> 5, dd = c & 31;
#pragma unroll
        for (int reg = 0; reg < 4; ++reg) {
          const int r = am0 + wr * 128 + m * 16 + lg * 4 + reg;
          if (r < M) {
            const int w = r / 49, nt = r - w * 49;
            dp[(((size_t)w * 16 + hh) * 49 + nt) * 32 + dd] =
                __float2bfloat16((acc[m][n][reg] + bvv) * sc);
          }
        }
      }
    }
  }
}

// ---------------- windowed attention: 1 head per wave, no barriers ---------
__global__ __launch_bounds__(256) void attn_win2(
    const bf16* __restrict__ q_ws, const bf16* __restrict__ k_ws,
    const bf16* __restrict__ vT_ws, const float* __restrict__ rpbL,
    const float* __restrict__ maskL, bf16* __restrict__ x_ws, int wstart) {
  __shared__ short sP[4][4096];
  const int tid = threadIdx.x, lane = tid & 63, wid = tid >> 6;
  const int l15 = lane & 15, lg = lane >> 4;
  const int wl = blockIdx.x;
  const int h = blockIdx.y * 4 + wid;
  const int wg = wstart + wl;
  char* Pl = (char*)sP[wid];
  const size_t base = ((size_t)wl * 16 + h) * 1568;
  const short8 z8 = (short8){0, 0, 0, 0, 0, 0, 0, 0};

  short8 qf[4], kf[4];
#pragma unroll
  for (int m = 0; m < 4; ++m) {
    const int r = m * 16 + l15;
    qf[m] = (r < 49) ? *(const short8*)(q_ws + base + r * 32 + lg * 8) : z8;
    kf[m] = (r < 49) ? *(const short8*)(k_ws + base + r * 32 + lg * 8) : z8;
  }
  f32x4 lc[4][4];
#pragma unroll
  for (int m = 0; m < 4; ++m)
#pragma unroll
    for (int n = 0; n < 4; ++n)
      lc[m][n] = __builtin_amdgcn_mfma_f32_16x16x32_bf16(
          qf[m], kf[n], (f32x4){0.f, 0.f, 0.f, 0.f}, 0, 0, 0);

  const f32x4* rbp = (const f32x4*)rpbL + (size_t)h * 1024 + lane;
  const f32x4* mkp = (const f32x4*)maskL + (size_t)(wg & 1023) * 1024 + lane;
#pragma unroll
  for (int m = 0; m < 4; ++m)
#pragma unroll
    for (int n = 0; n < 4; ++n) {
      const int mn = m * 4 + n;
      lc[m][n] += rbp[mn * 64] + mkp[mn * 64];
    }

#pragma unroll
  for (int m = 0; m < 4; ++m) {
#pragma unroll
    for (int reg = 0; reg < 4; ++reg) {
      float vmax = fmaxf(fmaxf(lc[m][0][reg], lc[m][1][reg]),
                         fmaxf(lc[m][2][reg], lc[m][3][reg]));
#pragma unroll
      for (int off = 1; off < 16; off <<= 1)
        vmax = fmaxf(vmax, __shfl_xor(vmax, off, 64));
      float e[4], ssum = 0.f;
#pragma unroll
      for (int n = 0; n < 4; ++n) {
        e[n] = __expf(lc[m][n][reg] - vmax);
        ssum += e[n];
      }
#pragma unroll
      for (int off = 1; off < 16; off <<= 1) ssum += __shfl_xor(ssum, off, 64);
      const float inv = __builtin_amdgcn_rcpf(ssum);
      const int i = m * 16 + lg * 4 + reg;
#pragma unroll
      for (int n = 0; n < 4; ++n) {
        const int cc = n * 16 + l15;
        *(unsigned short*)(Pl + i * 128 + ((2 * cc) ^ ((i & 7) << 4))) =
            f2b(e[n] * inv);
      }
    }
  }

  f32x4 xacc[4][2];
#pragma unroll
  for (int m = 0; m < 4; ++m)
#pragma unroll
    for (int n = 0; n < 2; ++n) xacc[m][n] = (f32x4){0.f, 0.f, 0.f, 0.f};
  const size_t vbase = ((size_t)wl * 16 + h) * 2048;
#pragma unroll
  for (int s = 0; s < 2; ++s) {
    short8 pf[4], vf[2];
#pragma unroll
    for (int m = 0; m < 4; ++m) {
      const int i = m * 16 + l15;
      pf[m] = *(const short8*)(Pl + i * 128 +
                               ((s * 64 + lg * 16) ^ ((i & 7) << 4)));
    }
#pragma unroll
    for (int n = 0; n < 2; ++n) {
      const int dd = n * 16 + l15;
      short8 vv = *(const short8*)(vT_ws + vbase + dd * 64 + s * 32 + lg * 8);
      if (s == 1) {
        if (lg == 3) vv = z8;
        else if (lg == 2) {
          vv[1] = 0; vv[2] = 0; vv[3] = 0; vv[4] = 0;
          vv[5] = 0; vv[6] = 0; vv[7] = 0;
        }
      }
      vf[n] = vv;
    }
#pragma unroll
    for (int m = 0; m < 4; ++m)
#pragma unroll
      for (int n = 0; n < 2; ++n)
        xacc[m][n] = __builtin_amdgcn_mfma_f32_16x16x32_bf16(
            pf[m], vf[n], xacc[m][n], 0, 0, 0);
  }

#pragma unroll
  for (int m = 0; m < 4; ++m)
#pragma unroll
    for (int n = 0; n < 2; ++n)
#pragma unroll
      for (int reg = 0; reg < 4; ++reg) {
        const int i = m * 16 + lg * 4 + reg;
        const int dd = n * 16 + l15;
        *(unsigned short*)(Pl + i * 80 + ((2 * dd) ^ ((i & 3) << 4))) =
            f2b(xacc[m][n][reg]);
      }
#pragma unroll
  for (int g = 0; g < 4; ++g) {
    const int row = g * 16 + (lane >> 2);
    if (row < 49) {
      const short8 xv = *(const short8*)(
          Pl + row * 80 + (((lane & 3) * 16) ^ ((row & 3) << 4)));
      *(short8*)(x_ws + ((size_t)wl * 49 + row) * 512 + h * 32 +
                 (lane & 3) * 8) = xv;
    }
  }
}

extern "C" void kernel_launch(void* const* d_in, const int* in_sizes, int n_in,
                              void* d_out, int out_size, void* d_ws,
                              size_t ws_size, hipStream_t stream) {
  const float* lf   = (const float*)d_in[0];
  const float* gfx  = (const float*)d_in[1];
  const float* mask = (const float*)d_in[2];
  const float* btab = (const float*)d_in[3];
  const float* Wk = (const float*)d_in[4];  const float* bk = (const float*)d_in[5];
  const float* Wq = (const float*)d_in[6];  const float* bq = (const float*)d_in[7];
  const float* Wv = (const float*)d_in[8];  const float* bv = (const float*)d_in[9];
  const float* Wp = (const float*)d_in[10]; const float* bp = (const float*)d_in[11];
  float* out = (float*)d_out;

  char* ws = (char*)d_ws;
  short* wbf = (short*)ws;  // 4 x 512x512 bf16 = 2 MB
  size_t off = (size_t)4 * 262144 * 2;
  float* rpbL = (float*)(ws + off); off += (size_t)16 * 4096 * 4;     // 256 KB
  float* maskL = (float*)(ws + off); off += (size_t)1024 * 4096 * 4;  // 16 MB

  const size_t perw = 2 * 49 * 1024 + 2 * 50176 + 65536;  // 266240 B/window
  size_t avail = (ws_size > off + 65536) ? ws_size - off - 65536 : 0;
  int CH = (int)((avail > 600000) ? (avail - 524288) / perw : 1);
  if (CH > 4096) CH = 4096;
  if (CH < 1) CH = 1;
  const int RWS = ((CH * 49 + 255) / 256) * 256;

  short* Al = (short*)(ws + off); off += (size_t)RWS * 1024;
  short* Ag = (short*)(ws + off); off += (size_t)RWS * 1024;
  bf16* q_ws = (bf16*)(ws + off); off += (size_t)CH * 50176;
  bf16* k_ws = (bf16*)(ws + off); off += (size_t)CH * 50176;
  bf16* vT_ws = (bf16*)(ws + off); off += (size_t)CH * 65536;
  bf16* x_ws = (bf16*)Al;  // alias: Al dead after gemm8p<0>

  cvt_w_kernel<<<256, 256, 0, stream>>>(Wk, Wq, Wv, Wp, (bf16*)wbf);
  prep_rpbL<<<64, 256, 0, stream>>>(btab, rpbL);
  prep_maskL<<<4096, 256, 0, stream>>>(mask, maskL);

  const float qscale = 0.17677669529663687f;  // 1/sqrt(32)
  for (int wstart = 0; wstart < 4096; wstart += CH) {
    const int nwin = (4096 - wstart < CH) ? (4096 - wstart) : CH;
    const int M = nwin * 49;
    const int gy = (M + 255) / 256;
    const int cg = (M * 64 + 255) / 256;
    cvt_a<<<cg, 256, 0, stream>>>(lf + (size_t)wstart * 25088, Al, M);
    cvt_a<<<cg, 256, 0, stream>>>(gfx + (size_t)wstart * 25088, Ag, M);
    gemm8p<0><<<6 * gy, 512, 0, stream>>>(Al, Ag, wbf, bk, bq, bv, qscale,
                                          k_ws, q_ws, vT_ws, nullptr, M);
    attn_win2<<<dim3(nwin, 4), 256, 0, stream>>>(q_ws, k_ws, vT_ws, rpbL,
                                                 maskL, x_ws, wstart);
    gemm8p<1><<<2 * gy, 512, 0, stream>>>((const short*)x_ws, nullptr, wbf,
                                          bp, nullptr, nullptr, 1.0f, nullptr,
                                          nullptr, nullptr,
                                          out + (size_t)wstart * 25088, M);
  }
}

// Round 10
// 1300.946 us; speedup vs baseline: 1.0153x; 1.0153x over previous
//
#include <hip/hip_runtime.h>
#include <hip/hip_bf16.h>

typedef __hip_bfloat16 bf16;
typedef __attribute__((ext_vector_type(4))) float f32x4;
typedef __attribute__((ext_vector_type(8))) short short8;
typedef __attribute__((ext_vector_type(4))) short short4v;

#define NEGBIG (-3.0e38f)

__device__ __forceinline__ unsigned short f2b(float x) {
  union { float f; unsigned int u; } v; v.f = x;
  unsigned int r = v.u + 0x7fffu + ((v.u >> 16) & 1u);
  return (unsigned short)(r >> 16);
}

__device__ __forceinline__ void gl16(const void* g, void* l) {
  __builtin_amdgcn_global_load_lds(
      (const __attribute__((address_space(1))) unsigned int*)g,
      (__attribute__((address_space(3))) unsigned int*)l, 16, 0, 0);
}

// bijective XCD-grouping swizzle (m204): contiguous tile range per XCD
__device__ __forceinline__ int xcd_swz(int orig, int nwg) {
  const int q = nwg >> 3, r = nwg & 7;
  const int xcd = orig & 7;
  const int base = (xcd < r) ? xcd * (q + 1) : r * (q + 1) + (xcd - r) * q;
  return base + (orig >> 3);
}

// ---------------- weight f32 -> bf16 (row-major) ----------------
__global__ __launch_bounds__(256) void cvt_w_kernel(
    const float* __restrict__ a, const float* __restrict__ b,
    const float* __restrict__ c, const float* __restrict__ d,
    bf16* __restrict__ dst) {
  const int t = blockIdx.x * 256 + threadIdx.x;
  const float* srcs[4] = {a, b, c, d};
#pragma unroll
  for (int w = 0; w < 4; ++w) {
    const f32x4 v = *(const f32x4*)(srcs[w] + (size_t)t * 4);
    short4v o;
    o[0] = (short)f2b(v[0]); o[1] = (short)f2b(v[1]);
    o[2] = (short)f2b(v[2]); o[3] = (short)f2b(v[3]);
    *(short4v*)((short*)dst + (size_t)w * 262144 + (size_t)t * 4) = o;
  }
}

// ---------------- activation f32 -> bf16 (row-major [M][512]) -------------
__global__ __launch_bounds__(256) void cvt_a(const float* __restrict__ src,
                                             short* __restrict__ dst, int M) {
  const int g = blockIdx.x * 256 + threadIdx.x;
  const int row = g >> 6, k8 = g & 63;
  if (row >= M) return;
  const float* sp = src + (size_t)row * 512 + k8 * 8;
  const f32x4 lo = *(const f32x4*)sp;
  const f32x4 hi = *(const f32x4*)(sp + 4);
  short8 u;
  u[0] = (short)f2b(lo[0]); u[1] = (short)f2b(lo[1]);
  u[2] = (short)f2b(lo[2]); u[3] = (short)f2b(lo[3]);
  u[4] = (short)f2b(hi[0]); u[5] = (short)f2b(hi[1]);
  u[6] = (short)f2b(hi[2]); u[7] = (short)f2b(hi[3]);
  *(short8*)(dst + (size_t)row * 512 + k8 * 8) = u;
}

// ---- bias table -> per-(head, frag-element) layout, pads = NEGBIG ----
__global__ __launch_bounds__(256) void prep_rpbL(const float* __restrict__ btab,
                                                 float* __restrict__ rpbL) {
  const int g = blockIdx.x * 256 + threadIdx.x;
  const int lane = g & 63, mn = (g >> 6) & 15, h = g >> 10;
  const int m = mn >> 2, n = mn & 3, l15 = lane & 15, lg = lane >> 4;
  const int cc = n * 16 + l15;
  const int aj = cc / 7, bj = cc % 7;
  f32x4 o;
#pragma unroll
  for (int reg = 0; reg < 4; ++reg) {
    const int i = m * 16 + lg * 4 + reg;
    if (i < 49 && cc < 49) {
      const int t = (i / 7 - aj + 6) * 13 + (i % 7 - bj + 6);
      o[reg] = btab[t * 16 + h];
    } else {
      o[reg] = NEGBIG;
    }
  }
  ((f32x4*)rpbL)[g] = o;
}

// ---- mask -> per-(window, frag-element) layout, pads = 0 ----
__global__ __launch_bounds__(256) void prep_maskL(const float* __restrict__ mask,
                                                  float* __restrict__ maskL) {
  const int g = blockIdx.x * 256 + threadIdx.x;
  const int lane = g & 63, mn = (g >> 6) & 15, wm = g >> 10;
  const int m = mn >> 2, n = mn & 3, l15 = lane & 15, lg = lane >> 4;
  const int cc = n * 16 + l15;
  f32x4 o;
#pragma unroll
  for (int reg = 0; reg < 4; ++reg) {
    const int i = m * 16 + lg * 4 + reg;
    o[reg] = (i < 49 && cc < 49) ? mask[(size_t)wm * 2401 + i * 49 + cc] : 0.f;
  }
  ((f32x4*)maskL)[g] = o;
}

// ------- m97-geometry staging: A 128x64 (16KB), B 256x64 (32KB), swizzled ----
__device__ __forceinline__ void stage_m97(const char* Ab, const char* Bb,
                                          char* As, char* Bs, int arow0,
                                          int brow0, int k0) {
  const int tid = threadIdx.x;  // 512 threads
#pragma unroll
  for (int i = 0; i < 2; ++i) {
    const int s = tid + 512 * i;  // A: 1024 slots of 16B
    const int row = s >> 3;
    const int sc = (s & 7) ^ (row & 7);
    gl16(Ab + (size_t)(arow0 + row) * 1024 + k0 * 2 + sc * 16, As + s * 16);
  }
#pragma unroll
  for (int i = 0; i < 4; ++i) {
    const int s = tid + 512 * i;  // B: 2048 slots of 16B
    const int row = s >> 3;
    const int sc = (s & 7) ^ (row & 7);
    gl16(Bb + (size_t)(brow0 + row) * 1024 + k0 * 2 + sc * 16, Bs + s * 16);
  }
}

// ---------------- fused KQV GEMM, m97 geometry ------------------------------
// grid 6*gy, XCD-swizzled; bn%6: cls = bn>>1 (0=K,1=Q,2=V^T), bnl = bn&1.
// BM=128 (tokens), BN=256 (channels), BK=64, 8 waves, single-buffer 48KB LDS
// -> 3 blocks/CU (24 waves). V^T via operand swap + remapped wave grid.
__global__ __launch_bounds__(512, 4) void gemm_kqv(
    const short* __restrict__ Al, const short* __restrict__ Ag,
    const short* __restrict__ wbf, const float* __restrict__ bk,
    const float* __restrict__ bq, const float* __restrict__ bv, float qscale,
    bf16* __restrict__ k_ws, bf16* __restrict__ q_ws, bf16* __restrict__ vT_ws,
    int M) {
  __shared__ char lds[49152];
  char* As = lds;           // [128][128B]
  char* Bs = lds + 16384;   // [256][128B]
  const int nwg = gridDim.x;
  const int t0 = xcd_swz(blockIdx.x, nwg);
  const int bn = t0 % 6, bm = t0 / 6;
  const int cls = bn >> 1, bnl = bn & 1;
  const int tid = threadIdx.x, lane = tid & 63, wid = tid >> 6;
  const int l15 = lane & 15, lg = lane >> 4;
  const bool swap = (cls == 2);
  const int wr = swap ? (wid & 3) : (wid >> 2);
  const int wc = swap ? (wid >> 2) : (wid & 3);
  const char* Ab = (const char*)((cls == 1) ? Ag : Al);
  const char* Bb = (const char*)(wbf + (size_t)cls * 262144);

  f32x4 acc[4][4];
#pragma unroll
  for (int m = 0; m < 4; ++m)
#pragma unroll
    for (int n = 0; n < 4; ++n) acc[m][n] = (f32x4){0.f, 0.f, 0.f, 0.f};

  const char* fam = swap ? Bs : As;
  const char* fbm = swap ? As : Bs;

  for (int kt = 0; kt < 8; ++kt) {
    stage_m97(Ab, Bb, As, Bs, bm * 128, bnl * 256, kt * 64);
    __syncthreads();
#pragma unroll
    for (int s = 0; s < 2; ++s) {
      short8 af[4], bfr[4];
#pragma unroll
      for (int m = 0; m < 4; ++m) {
        const int r = wr * 64 + m * 16 + l15;
        af[m] = *(const short8*)(fam + r * 128 +
                                 (((s * 4 + lg) ^ (r & 7)) << 4));
      }
#pragma unroll
      for (int n = 0; n < 4; ++n) {
        const int r = wc * 64 + n * 16 + l15;
        bfr[n] = *(const short8*)(fbm + r * 128 +
                                  (((s * 4 + lg) ^ (r & 7)) << 4));
      }
#pragma unroll
      for (int m = 0; m < 4; ++m)
#pragma unroll
        for (int n = 0; n < 4; ++n)
          acc[m][n] = __builtin_amdgcn_mfma_f32_16x16x32_bf16(
              af[m], bfr[n], acc[m][n], 0, 0, 0);
    }
    __syncthreads();
  }

  if (cls == 2) {  // V^T: m-axis = channels (256), n-axis = tokens (128)
#pragma unroll
    for (int m = 0; m < 4; ++m) {
#pragma unroll
      for (int n = 0; n < 4; ++n) {
        const int tok = bm * 128 + wc * 64 + n * 16 + l15;
        if (tok < M) {
          const int w = tok / 49, nt = tok - w * 49;
#pragma unroll
          for (int reg = 0; reg < 4; ++reg) {
            const int ch = bnl * 256 + wr * 64 + m * 16 + lg * 4 + reg;
            const float v = acc[m][n][reg] + bv[ch];
            const int hh = ch >> 5, dd = ch & 31;
            vT_ws[(((size_t)w * 16 + hh) * 32 + dd) * 64 + nt] =
                __float2bfloat16(v);
          }
        }
      }
    }
  } else {
    const float* bb = (cls == 0) ? bk : bq;
    bf16* dp = (cls == 0) ? k_ws : q_ws;
    const float sc = (cls == 0) ? 1.0f : qscale;
#pragma unroll
    for (int m = 0; m < 4; ++m) {
#pragma unroll
      for (int n = 0; n < 4; ++n) {
        const int c = bnl * 256 + wc * 64 + n * 16 + l15;
        const float bvv = bb[c];
        const int hh = c >> 5, dd = c & 31;
#pragma unroll
        for (int reg = 0; reg < 4; ++reg) {
          const int r = bm * 128 + wr * 64 + m * 16 + lg * 4 + reg;
          if (r < M) {
            const int w = r / 49, nt = r - w * 49;
            dp[(((size_t)w * 16 + hh) * 49 + nt) * 32 + dd] =
                __float2bfloat16((acc[m][n][reg] + bvv) * sc);
          }
        }
      }
    }
  }
}

// ---------------- proj GEMM, m97 geometry: f32 out [r][512] -----------------
__global__ __launch_bounds__(512, 4) void gemm_p(const short* __restrict__ Abf,
                                                 const short* __restrict__ Bbf,
                                                 const float* __restrict__ bias,
                                                 float* __restrict__ dst,
                                                 int M) {
  __shared__ char lds[49152];
  char* As = lds;
  char* Bs = lds + 16384;
  const int nwg = gridDim.x;
  const int t0 = xcd_swz(blockIdx.x, nwg);
  const int bnl = t0 & 1, bm = t0 >> 1;
  const int tid = threadIdx.x, lane = tid & 63, wid = tid >> 6;
  const int wr = wid >> 2, wc = wid & 3, l15 = lane & 15, lg = lane >> 4;

  f32x4 acc[4][4];
#pragma unroll
  for (int m = 0; m < 4; ++m)
#pragma unroll
    for (int n = 0; n < 4; ++n) acc[m][n] = (f32x4){0.f, 0.f, 0.f, 0.f};

  for (int kt = 0; kt < 8; ++kt) {
    stage_m97((const char*)Abf, (const char*)Bbf, As, Bs, bm * 128, bnl * 256,
              kt * 64);
    __syncthreads();
#pragma unroll
    for (int s = 0; s < 2; ++s) {
      short8 af[4], bfr[4];
#pragma unroll
      for (int m = 0; m < 4; ++m) {
        const int r = wr * 64 + m * 16 + l15;
        af[m] = *(const short8*)(As + r * 128 +
                                 (((s * 4 + lg) ^ (r & 7)) << 4));
      }
#pragma unroll
      for (int n = 0; n < 4; ++n) {
        const int r = wc * 64 + n * 16 + l15;
        bfr[n] = *(const short8*)(Bs + r * 128 +
                                  (((s * 4 + lg) ^ (r & 7)) << 4));
      }
#pragma unroll
      for (int m = 0; m < 4; ++m)
#pragma unroll
        for (int n = 0; n < 4; ++n)
          acc[m][n] = __builtin_amdgcn_mfma_f32_16x16x32_bf16(
              af[m], bfr[n], acc[m][n], 0, 0, 0);
    }
    __syncthreads();
  }

#pragma unroll
  for (int m = 0; m < 4; ++m) {
#pragma unroll
    for (int n = 0; n < 4; ++n) {
      const int c = bnl * 256 + wc * 64 + n * 16 + l15;
      const float bvv = bias[c];
#pragma unroll
      for (int reg = 0; reg < 4; ++reg) {
        const int r = bm * 128 + wr * 64 + m * 16 + lg * 4 + reg;
        if (r < M) dst[(size_t)r * 512 + c] = acc[m][n][reg] + bvv;
      }
    }
  }
}

// ---------------- windowed attention: 1 head per wave, no barriers ---------
__global__ __launch_bounds__(256) void attn_win2(
    const bf16* __restrict__ q_ws, const bf16* __restrict__ k_ws,
    const bf16* __restrict__ vT_ws, const float* __restrict__ rpbL,
    const float* __restrict__ maskL, bf16* __restrict__ x_ws, int wstart) {
  __shared__ short sP[4][4096];
  const int tid = threadIdx.x, lane = tid & 63, wid = tid >> 6;
  const int l15 = lane & 15, lg = lane >> 4;
  const int wl = blockIdx.x;
  const int h = blockIdx.y * 4 + wid;
  const int wg = wstart + wl;
  char* Pl = (char*)sP[wid];
  const size_t base = ((size_t)wl * 16 + h) * 1568;
  const short8 z8 = (short8){0, 0, 0, 0, 0, 0, 0, 0};

  short8 qf[4], kf[4];
#pragma unroll
  for (int m = 0; m < 4; ++m) {
    const int r = m * 16 + l15;
    qf[m] = (r < 49) ? *(const short8*)(q_ws + base + r * 32 + lg * 8) : z8;
    kf[m] = (r < 49) ? *(const short8*)(k_ws + base + r * 32 + lg * 8) : z8;
  }
  f32x4 lc[4][4];
#pragma unroll
  for (int m = 0; m < 4; ++m)
#pragma unroll
    for (int n = 0; n < 4; ++n)
      lc[m][n] = __builtin_amdgcn_mfma_f32_16x16x32_bf16(
          qf[m], kf[n], (f32x4){0.f, 0.f, 0.f, 0.f}, 0, 0, 0);

  const f32x4* rbp = (const f32x4*)rpbL + (size_t)h * 1024 + lane;
  const f32x4* mkp = (const f32x4*)maskL + (size_t)(wg & 1023) * 1024 + lane;
#pragma unroll
  for (int m = 0; m < 4; ++m)
#pragma unroll
    for (int n = 0; n < 4; ++n) {
      const int mn = m * 4 + n;
      lc[m][n] += rbp[mn * 64] + mkp[mn * 64];
    }

#pragma unroll
  for (int m = 0; m < 4; ++m) {
#pragma unroll
    for (int reg = 0; reg < 4; ++reg) {
      float vmax = fmaxf(fmaxf(lc[m][0][reg], lc[m][1][reg]),
                         fmaxf(lc[m][2][reg], lc[m][3][reg]));
#pragma unroll
      for (int off = 1; off < 16; off <<= 1)
        vmax = fmaxf(vmax, __shfl_xor(vmax, off, 64));
      float e[4], ssum = 0.f;
#pragma unroll
      for (int n = 0; n < 4; ++n) {
        e[n] = __expf(lc[m][n][reg] - vmax);
        ssum += e[n];
      }
#pragma unroll
      for (int off = 1; off < 16; off <<= 1) ssum += __shfl_xor(ssum, off, 64);
      const float inv = __builtin_amdgcn_rcpf(ssum);
      const int i = m * 16 + lg * 4 + reg;
#pragma unroll
      for (int n = 0; n < 4; ++n) {
        const int cc = n * 16 + l15;
        *(unsigned short*)(Pl + i * 128 + ((2 * cc) ^ ((i & 7) << 4))) =
            f2b(e[n] * inv);
      }
    }
  }

  f32x4 xacc[4][2];
#pragma unroll
  for (int m = 0; m < 4; ++m)
#pragma unroll
    for (int n = 0; n < 2; ++n) xacc[m][n] = (f32x4){0.f, 0.f, 0.f, 0.f};
  const size_t vbase = ((size_t)wl * 16 + h) * 2048;
#pragma unroll
  for (int s = 0; s < 2; ++s) {
    short8 pf[4], vf[2];
#pragma unroll
    for (int m = 0; m < 4; ++m) {
      const int i = m * 16 + l15;
      pf[m] = *(const short8*)(Pl + i * 128 +
                               ((s * 64 + lg * 16) ^ ((i & 7) << 4)));
    }
#pragma unroll
    for (int n = 0; n < 2; ++n) {
      const int dd = n * 16 + l15;
      short8 vv = *(const short8*)(vT_ws + vbase + dd * 64 + s * 32 + lg * 8);
      if (s == 1) {
        if (lg == 3) vv = z8;
        else if (lg == 2) {
          vv[1] = 0; vv[2] = 0; vv[3] = 0; vv[4] = 0;
          vv[5] = 0; vv[6] = 0; vv[7] = 0;
        }
      }
      vf[n] = vv;
    }
#pragma unroll
    for (int m = 0; m < 4; ++m)
#pragma unroll
      for (int n = 0; n < 2; ++n)
        xacc[m][n] = __builtin_amdgcn_mfma_f32_16x16x32_bf16(
            pf[m], vf[n], xacc[m][n], 0, 0, 0);
  }

#pragma unroll
  for (int m = 0; m < 4; ++m)
#pragma unroll
    for (int n = 0; n < 2; ++n)
#pragma unroll
      for (int reg = 0; reg < 4; ++reg) {
        const int i = m * 16 + lg * 4 + reg;
        const int dd = n * 16 + l15;
        *(unsigned short*)(Pl + i * 80 + ((2 * dd) ^ ((i & 3) << 4))) =
            f2b(xacc[m][n][reg]);
      }
#pragma unroll
  for (int g = 0; g < 4; ++g) {
    const int row = g * 16 + (lane >> 2);
    if (row < 49) {
      const short8 xv = *(const short8*)(
          Pl + row * 80 + (((lane & 3) * 16) ^ ((row & 3) << 4)));
      *(short8*)(x_ws + ((size_t)wl * 49 + row) * 512 + h * 32 +
                 (lane & 3) * 8) = xv;
    }
  }
}

extern "C" void kernel_launch(void* const* d_in, const int* in_sizes, int n_in,
                              void* d_out, int out_size, void* d_ws,
                              size_t ws_size, hipStream_t stream) {
  const float* lf   = (const float*)d_in[0];
  const float* gfx  = (const float*)d_in[1];
  const float* mask = (const float*)d_in[2];
  const float* btab = (const float*)d_in[3];
  const float* Wk = (const float*)d_in[4];  const float* bk = (const float*)d_in[5];
  const float* Wq = (const float*)d_in[6];  const float* bq = (const float*)d_in[7];
  const float* Wv = (const float*)d_in[8];  const float* bv = (const float*)d_in[9];
  const float* Wp = (const float*)d_in[10]; const float* bp = (const float*)d_in[11];
  float* out = (float*)d_out;

  char* ws = (char*)d_ws;
  short* wbf = (short*)ws;  // 4 x 512x512 bf16 = 2 MB
  size_t off = (size_t)4 * 262144 * 2;
  float* rpbL = (float*)(ws + off); off += (size_t)16 * 4096 * 4;     // 256 KB
  float* maskL = (float*)(ws + off); off += (size_t)1024 * 4096 * 4;  // 16 MB

  const size_t perw = 2 * 49 * 1024 + 2 * 50176 + 65536;  // 266240 B/window
  size_t avail = (ws_size > off + 65536) ? ws_size - off - 65536 : 0;
  int CH = (int)((avail > 300000) ? (avail - 262144) / perw : 1);
  // L3-resident chunking: keep per-chunk intermediates (~136 MB @512) inside
  // the 256 MB Infinity Cache so gemm->attn->proj hops never touch HBM.
  if (CH > 512) CH = 512;
  if (CH < 1) CH = 1;
  const int RWS = ((CH * 49 + 127) / 128) * 128;

  short* Al = (short*)(ws + off); off += (size_t)RWS * 1024;
  short* Ag = (short*)(ws + off); off += (size_t)RWS * 1024;
  bf16* q_ws = (bf16*)(ws + off); off += (size_t)CH * 50176;
  bf16* k_ws = (bf16*)(ws + off); off += (size_t)CH * 50176;
  bf16* vT_ws = (bf16*)(ws + off); off += (size_t)CH * 65536;
  bf16* x_ws = (bf16*)Al;  // alias: Al dead after gemm_kqv

  cvt_w_kernel<<<256, 256, 0, stream>>>(Wk, Wq, Wv, Wp, (bf16*)wbf);
  prep_rpbL<<<64, 256, 0, stream>>>(btab, rpbL);
  prep_maskL<<<4096, 256, 0, stream>>>(mask, maskL);

  const float qscale = 0.17677669529663687f;  // 1/sqrt(32)
  for (int wstart = 0; wstart < 4096; wstart += CH) {
    const int nwin = (4096 - wstart < CH) ? (4096 - wstart) : CH;
    const int M = nwin * 49;
    const int gy = (M + 127) / 128;
    const int cg = (M * 64 + 255) / 256;
    cvt_a<<<cg, 256, 0, stream>>>(lf + (size_t)wstart * 25088, Al, M);
    cvt_a<<<cg, 256, 0, stream>>>(gfx + (size_t)wstart * 25088, Ag, M);
    gemm_kqv<<<6 * gy, 512, 0, stream>>>(Al, Ag, wbf, bk, bq, bv, qscale,
                                         k_ws, q_ws, vT_ws, M);
    attn_win2<<<dim3(nwin, 4), 256, 0, stream>>>(q_ws, k_ws, vT_ws, rpbL,
                                                 maskL, x_ws, wstart);
    gemm_p<<<2 * gy, 512, 0, stream>>>((const short*)x_ws, wbf + 3 * 262144,
                                       bp, out + (size_t)wstart * 25088, M);
  }
}

// Round 11
// 1282.612 us; speedup vs baseline: 1.0298x; 1.0143x over previous
//
#include <hip/hip_runtime.h>
#include <hip/hip_bf16.h>

typedef __hip_bfloat16 bf16;
typedef __attribute__((ext_vector_type(4))) float f32x4;
typedef __attribute__((ext_vector_type(8))) short short8;
typedef __attribute__((ext_vector_type(4))) short short4v;

#define NEGBIG (-3.0e38f)

__device__ __forceinline__ unsigned short f2b(float x) {
  union { float f; unsigned int u; } v; v.f = x;
  unsigned int r = v.u + 0x7fffu + ((v.u >> 16) & 1u);
  return (unsigned short)(r >> 16);
}

__device__ __forceinline__ void gl16(const void* g, void* l) {
  __builtin_amdgcn_global_load_lds(
      (const __attribute__((address_space(1))) unsigned int*)g,
      (__attribute__((address_space(3))) unsigned int*)l, 16, 0, 0);
}

// bijective XCD-grouping swizzle (m204): contiguous tile range per XCD
__device__ __forceinline__ int xcd_swz(int orig, int nwg) {
  const int q = nwg >> 3, r = nwg & 7;
  const int xcd = orig & 7;
  const int base = (xcd < r) ? xcd * (q + 1) : r * (q + 1) + (xcd - r) * q;
  return base + (orig >> 3);
}

// ---------------- weight f32 -> bf16 (row-major) ----------------
__global__ __launch_bounds__(256) void cvt_w_kernel(
    const float* __restrict__ a, const float* __restrict__ b,
    const float* __restrict__ c, const float* __restrict__ d,
    bf16* __restrict__ dst) {
  const int t = blockIdx.x * 256 + threadIdx.x;
  const float* srcs[4] = {a, b, c, d};
#pragma unroll
  for (int w = 0; w < 4; ++w) {
    const f32x4 v = *(const f32x4*)(srcs[w] + (size_t)t * 4);
    short4v o;
    o[0] = (short)f2b(v[0]); o[1] = (short)f2b(v[1]);
    o[2] = (short)f2b(v[2]); o[3] = (short)f2b(v[3]);
    *(short4v*)((short*)dst + (size_t)w * 262144 + (size_t)t * 4) = o;
  }
}

// ---------------- activation f32 -> bf16 (row-major [M][512]) -------------
__global__ __launch_bounds__(256) void cvt_a(const float* __restrict__ src,
                                             short* __restrict__ dst, int M) {
  const int g = blockIdx.x * 256 + threadIdx.x;
  const int row = g >> 6, k8 = g & 63;
  if (row >= M) return;
  const float* sp = src + (size_t)row * 512 + k8 * 8;
  const f32x4 lo = *(const f32x4*)sp;
  const f32x4 hi = *(const f32x4*)(sp + 4);
  short8 u;
  u[0] = (short)f2b(lo[0]); u[1] = (short)f2b(lo[1]);
  u[2] = (short)f2b(lo[2]); u[3] = (short)f2b(lo[3]);
  u[4] = (short)f2b(hi[0]); u[5] = (short)f2b(hi[1]);
  u[6] = (short)f2b(hi[2]); u[7] = (short)f2b(hi[3]);
  *(short8*)(dst + (size_t)row * 512 + k8 * 8) = u;
}

// ---- bias table -> per-(head, frag-element) layout, pads = NEGBIG ----
__global__ __launch_bounds__(256) void prep_rpbL(const float* __restrict__ btab,
                                                 float* __restrict__ rpbL) {
  const int g = blockIdx.x * 256 + threadIdx.x;
  const int lane = g & 63, mn = (g >> 6) & 15, h = g >> 10;
  const int m = mn >> 2, n = mn & 3, l15 = lane & 15, lg = lane >> 4;
  const int cc = n * 16 + l15;
  const int aj = cc / 7, bj = cc % 7;
  f32x4 o;
#pragma unroll
  for (int reg = 0; reg < 4; ++reg) {
    const int i = m * 16 + lg * 4 + reg;
    if (i < 49 && cc < 49) {
      const int t = (i / 7 - aj + 6) * 13 + (i % 7 - bj + 6);
      o[reg] = btab[t * 16 + h];
    } else {
      o[reg] = NEGBIG;
    }
  }
  ((f32x4*)rpbL)[g] = o;
}

// ---- mask -> per-(window, frag-element) layout, pads = 0 ----
__global__ __launch_bounds__(256) void prep_maskL(const float* __restrict__ mask,
                                                  float* __restrict__ maskL) {
  const int g = blockIdx.x * 256 + threadIdx.x;
  const int lane = g & 63, mn = (g >> 6) & 15, wm = g >> 10;
  const int m = mn >> 2, n = mn & 3, l15 = lane & 15, lg = lane >> 4;
  const int cc = n * 16 + l15;
  f32x4 o;
#pragma unroll
  for (int reg = 0; reg < 4; ++reg) {
    const int i = m * 16 + lg * 4 + reg;
    o[reg] = (i < 49 && cc < 49) ? mask[(size_t)wm * 2401 + i * 49 + cc] : 0.f;
  }
  ((f32x4*)maskL)[g] = o;
}

// ------- m97-geometry staging: A 128x64 (16KB), B 256x64 (32KB), swizzled ----
__device__ __forceinline__ void stage_m97(const char* Ab, const char* Bb,
                                          char* As, char* Bs, int arow0,
                                          int brow0, int k0) {
  const int tid = threadIdx.x;  // 512 threads
#pragma unroll
  for (int i = 0; i < 2; ++i) {
    const int s = tid + 512 * i;  // A: 1024 slots of 16B
    const int row = s >> 3;
    const int sc = (s & 7) ^ (row & 7);
    gl16(Ab + (size_t)(arow0 + row) * 1024 + k0 * 2 + sc * 16, As + s * 16);
  }
#pragma unroll
  for (int i = 0; i < 4; ++i) {
    const int s = tid + 512 * i;  // B: 2048 slots of 16B
    const int row = s >> 3;
    const int sc = (s & 7) ^ (row & 7);
    gl16(Bb + (size_t)(brow0 + row) * 1024 + k0 * 2 + sc * 16, Bs + s * 16);
  }
}

// ---------------- fused KQV GEMM, m97 geometry ------------------------------
__global__ __launch_bounds__(512, 4) void gemm_kqv(
    const short* __restrict__ Al, const short* __restrict__ Ag,
    const short* __restrict__ wbf, const float* __restrict__ bk,
    const float* __restrict__ bq, const float* __restrict__ bv, float qscale,
    bf16* __restrict__ k_ws, bf16* __restrict__ q_ws, bf16* __restrict__ vT_ws,
    int M) {
  __shared__ char lds[49152];
  char* As = lds;           // [128][128B]
  char* Bs = lds + 16384;   // [256][128B]
  const int nwg = gridDim.x;
  const int t0 = xcd_swz(blockIdx.x, nwg);
  const int bn = t0 % 6, bm = t0 / 6;
  const int cls = bn >> 1, bnl = bn & 1;
  const int tid = threadIdx.x, lane = tid & 63, wid = tid >> 6;
  const int l15 = lane & 15, lg = lane >> 4;
  const bool swap = (cls == 2);
  const int wr = swap ? (wid & 3) : (wid >> 2);
  const int wc = swap ? (wid >> 2) : (wid & 3);
  const char* Ab = (const char*)((cls == 1) ? Ag : Al);
  const char* Bb = (const char*)(wbf + (size_t)cls * 262144);

  f32x4 acc[4][4];
#pragma unroll
  for (int m = 0; m < 4; ++m)
#pragma unroll
    for (int n = 0; n < 4; ++n) acc[m][n] = (f32x4){0.f, 0.f, 0.f, 0.f};

  const char* fam = swap ? Bs : As;
  const char* fbm = swap ? As : Bs;

  for (int kt = 0; kt < 8; ++kt) {
    stage_m97(Ab, Bb, As, Bs, bm * 128, bnl * 256, kt * 64);
    __syncthreads();
#pragma unroll
    for (int s = 0; s < 2; ++s) {
      short8 af[4], bfr[4];
#pragma unroll
      for (int m = 0; m < 4; ++m) {
        const int r = wr * 64 + m * 16 + l15;
        af[m] = *(const short8*)(fam + r * 128 +
                                 (((s * 4 + lg) ^ (r & 7)) << 4));
      }
#pragma unroll
      for (int n = 0; n < 4; ++n) {
        const int r = wc * 64 + n * 16 + l15;
        bfr[n] = *(const short8*)(fbm + r * 128 +
                                  (((s * 4 + lg) ^ (r & 7)) << 4));
      }
#pragma unroll
      for (int m = 0; m < 4; ++m)
#pragma unroll
        for (int n = 0; n < 4; ++n)
          acc[m][n] = __builtin_amdgcn_mfma_f32_16x16x32_bf16(
              af[m], bfr[n], acc[m][n], 0, 0, 0);
    }
    __syncthreads();
  }

  if (cls == 2) {  // V^T: m-axis = channels (256), n-axis = tokens (128)
#pragma unroll
    for (int m = 0; m < 4; ++m) {
#pragma unroll
      for (int n = 0; n < 4; ++n) {
        const int tok = bm * 128 + wc * 64 + n * 16 + l15;
        if (tok < M) {
          const int w = tok / 49, nt = tok - w * 49;
#pragma unroll
          for (int reg = 0; reg < 4; ++reg) {
            const int ch = bnl * 256 + wr * 64 + m * 16 + lg * 4 + reg;
            const float v = acc[m][n][reg] + bv[ch];
            const int hh = ch >> 5, dd = ch & 31;
            vT_ws[(((size_t)w * 16 + hh) * 32 + dd) * 64 + nt] =
                __float2bfloat16(v);
          }
        }
      }
    }
  } else {
    const float* bb = (cls == 0) ? bk : bq;
    bf16* dp = (cls == 0) ? k_ws : q_ws;
    const float sc = (cls == 0) ? 1.0f : qscale;
#pragma unroll
    for (int m = 0; m < 4; ++m) {
#pragma unroll
      for (int n = 0; n < 4; ++n) {
        const int c = bnl * 256 + wc * 64 + n * 16 + l15;
        const float bvv = bb[c];
        const int hh = c >> 5, dd = c & 31;
#pragma unroll
        for (int reg = 0; reg < 4; ++reg) {
          const int r = bm * 128 + wr * 64 + m * 16 + lg * 4 + reg;
          if (r < M) {
            const int w = r / 49, nt = r - w * 49;
            dp[(((size_t)w * 16 + hh) * 49 + nt) * 32 + dd] =
                __float2bfloat16((acc[m][n][reg] + bvv) * sc);
          }
        }
      }
    }
  }
}

// ---------------- proj GEMM, m97 geometry: f32 out [r][512] -----------------
__global__ __launch_bounds__(512, 4) void gemm_p(const short* __restrict__ Abf,
                                                 const short* __restrict__ Bbf,
                                                 const float* __restrict__ bias,
                                                 float* __restrict__ dst,
                                                 int M) {
  __shared__ char lds[49152];
  char* As = lds;
  char* Bs = lds + 16384;
  const int nwg = gridDim.x;
  const int t0 = xcd_swz(blockIdx.x, nwg);
  const int bnl = t0 & 1, bm = t0 >> 1;
  const int tid = threadIdx.x, lane = tid & 63, wid = tid >> 6;
  const int wr = wid >> 2, wc = wid & 3, l15 = lane & 15, lg = lane >> 4;

  f32x4 acc[4][4];
#pragma unroll
  for (int m = 0; m < 4; ++m)
#pragma unroll
    for (int n = 0; n < 4; ++n) acc[m][n] = (f32x4){0.f, 0.f, 0.f, 0.f};

  for (int kt = 0; kt < 8; ++kt) {
    stage_m97((const char*)Abf, (const char*)Bbf, As, Bs, bm * 128, bnl * 256,
              kt * 64);
    __syncthreads();
#pragma unroll
    for (int s = 0; s < 2; ++s) {
      short8 af[4], bfr[4];
#pragma unroll
      for (int m = 0; m < 4; ++m) {
        const int r = wr * 64 + m * 16 + l15;
        af[m] = *(const short8*)(As + r * 128 +
                                 (((s * 4 + lg) ^ (r & 7)) << 4));
      }
#pragma unroll
      for (int n = 0; n < 4; ++n) {
        const int r = wc * 64 + n * 16 + l15;
        bfr[n] = *(const short8*)(Bs + r * 128 +
                                  (((s * 4 + lg) ^ (r & 7)) << 4));
      }
#pragma unroll
      for (int m = 0; m < 4; ++m)
#pragma unroll
        for (int n = 0; n < 4; ++n)
          acc[m][n] = __builtin_amdgcn_mfma_f32_16x16x32_bf16(
              af[m], bfr[n], acc[m][n], 0, 0, 0);
    }
    __syncthreads();
  }

#pragma unroll
  for (int m = 0; m < 4; ++m) {
#pragma unroll
    for (int n = 0; n < 4; ++n) {
      const int c = bnl * 256 + wc * 64 + n * 16 + l15;
      const float bvv = bias[c];
#pragma unroll
      for (int reg = 0; reg < 4; ++reg) {
        const int r = bm * 128 + wr * 64 + m * 16 + lg * 4 + reg;
        if (r < M) dst[(size_t)r * 512 + c] = acc[m][n][reg] + bvv;
      }
    }
  }
}

// ---------------- windowed attention v3: 8 heads/block, mask staged in LDS --
// grid (nwin, 2), 512 thr / 8 waves (1 head each). The window's 16KB
// frag-layout mask is loaded ONCE per block via global_load_lds (overlapped
// with QK^T), killing the 16x per-wave mask fan-out (1.07 GB -> 134 MB).
__global__ __launch_bounds__(512) void attn_win3(
    const bf16* __restrict__ q_ws, const bf16* __restrict__ k_ws,
    const bf16* __restrict__ vT_ws, const float* __restrict__ rpbL,
    const float* __restrict__ maskL, bf16* __restrict__ x_ws, int wstart) {
  __shared__ char smk[16384];    // window mask frags (1024 x f32x4)
  __shared__ short sP[8][4096];  // per-wave P / X staging
  const int tid = threadIdx.x, lane = tid & 63, wid = tid >> 6;
  const int l15 = lane & 15, lg = lane >> 4;
  const int wl = blockIdx.x;
  const int h = blockIdx.y * 8 + wid;
  const int wg = wstart + wl;
  char* Pl = (char*)sP[wid];
  const size_t base = ((size_t)wl * 16 + h) * 1568;
  const short8 z8 = (short8){0, 0, 0, 0, 0, 0, 0, 0};

  // issue mask stage first; its vmcnt-wait lands at the __syncthreads below,
  // hidden under the Q/K loads + 16 MFMAs.
  {
    const char* msrc = (const char*)(maskL + (size_t)(wg & 1023) * 4096);
    gl16(msrc + tid * 16, smk + tid * 16);
    gl16(msrc + 8192 + tid * 16, smk + 8192 + tid * 16);
  }

  short8 qf[4], kf[4];
#pragma unroll
  for (int m = 0; m < 4; ++m) {
    const int r = m * 16 + l15;
    qf[m] = (r < 49) ? *(const short8*)(q_ws + base + r * 32 + lg * 8) : z8;
    kf[m] = (r < 49) ? *(const short8*)(k_ws + base + r * 32 + lg * 8) : z8;
  }
  f32x4 lc[4][4];
#pragma unroll
  for (int m = 0; m < 4; ++m)
#pragma unroll
    for (int n = 0; n < 4; ++n)
      lc[m][n] = __builtin_amdgcn_mfma_f32_16x16x32_bf16(
          qf[m], kf[n], (f32x4){0.f, 0.f, 0.f, 0.f}, 0, 0, 0);

  __syncthreads();  // mask frags resident

  const f32x4* rbp = (const f32x4*)rpbL + (size_t)h * 1024 + lane;
  const f32x4* mks = (const f32x4*)smk + lane;
#pragma unroll
  for (int m = 0; m < 4; ++m)
#pragma unroll
    for (int n = 0; n < 4; ++n) {
      const int mn = m * 4 + n;
      lc[m][n] += rbp[mn * 64] + mks[mn * 64];
    }

#pragma unroll
  for (int m = 0; m < 4; ++m) {
#pragma unroll
    for (int reg = 0; reg < 4; ++reg) {
      float vmax = fmaxf(fmaxf(lc[m][0][reg], lc[m][1][reg]),
                         fmaxf(lc[m][2][reg], lc[m][3][reg]));
#pragma unroll
      for (int off = 1; off < 16; off <<= 1)
        vmax = fmaxf(vmax, __shfl_xor(vmax, off, 64));
      float e[4], ssum = 0.f;
#pragma unroll
      for (int n = 0; n < 4; ++n) {
        e[n] = __expf(lc[m][n][reg] - vmax);
        ssum += e[n];
      }
#pragma unroll
      for (int off = 1; off < 16; off <<= 1) ssum += __shfl_xor(ssum, off, 64);
      const float inv = __builtin_amdgcn_rcpf(ssum);
      const int i = m * 16 + lg * 4 + reg;
#pragma unroll
      for (int n = 0; n < 4; ++n) {
        const int cc = n * 16 + l15;
        *(unsigned short*)(Pl + i * 128 + ((2 * cc) ^ ((i & 7) << 4))) =
            f2b(e[n] * inv);
      }
    }
  }

  f32x4 xacc[4][2];
#pragma unroll
  for (int m = 0; m < 4; ++m)
#pragma unroll
    for (int n = 0; n < 2; ++n) xacc[m][n] = (f32x4){0.f, 0.f, 0.f, 0.f};
  const size_t vbase = ((size_t)wl * 16 + h) * 2048;
#pragma unroll
  for (int s = 0; s < 2; ++s) {
    short8 pf[4], vf[2];
#pragma unroll
    for (int m = 0; m < 4; ++m) {
      const int i = m * 16 + l15;
      pf[m] = *(const short8*)(Pl + i * 128 +
                               ((s * 64 + lg * 16) ^ ((i & 7) << 4)));
    }
#pragma unroll
    for (int n = 0; n < 2; ++n) {
      const int dd = n * 16 + l15;
      short8 vv = *(const short8*)(vT_ws + vbase + dd * 64 + s * 32 + lg * 8);
      if (s == 1) {
        if (lg == 3) vv = z8;
        else if (lg == 2) {
          vv[1] = 0; vv[2] = 0; vv[3] = 0; vv[4] = 0;
          vv[5] = 0; vv[6] = 0; vv[7] = 0;
        }
      }
      vf[n] = vv;
    }
#pragma unroll
    for (int m = 0; m < 4; ++m)
#pragma unroll
      for (int n = 0; n < 2; ++n)
        xacc[m][n] = __builtin_amdgcn_mfma_f32_16x16x32_bf16(
            pf[m], vf[n], xacc[m][n], 0, 0, 0);
  }

#pragma unroll
  for (int m = 0; m < 4; ++m)
#pragma unroll
    for (int n = 0; n < 2; ++n)
#pragma unroll
      for (int reg = 0; reg < 4; ++reg) {
        const int i = m * 16 + lg * 4 + reg;
        const int dd = n * 16 + l15;
        *(unsigned short*)(Pl + i * 80 + ((2 * dd) ^ ((i & 3) << 4))) =
            f2b(xacc[m][n][reg]);
      }
#pragma unroll
  for (int g = 0; g < 4; ++g) {
    const int row = g * 16 + (lane >> 2);
    if (row < 49) {
      const short8 xv = *(const short8*)(
          Pl + row * 80 + (((lane & 3) * 16) ^ ((row & 3) << 4)));
      *(short8*)(x_ws + ((size_t)wl * 49 + row) * 512 + h * 32 +
                 (lane & 3) * 8) = xv;
    }
  }
}

extern "C" void kernel_launch(void* const* d_in, const int* in_sizes, int n_in,
                              void* d_out, int out_size, void* d_ws,
                              size_t ws_size, hipStream_t stream) {
  const float* lf   = (const float*)d_in[0];
  const float* gfx  = (const float*)d_in[1];
  const float* mask = (const float*)d_in[2];
  const float* btab = (const float*)d_in[3];
  const float* Wk = (const float*)d_in[4];  const float* bk = (const float*)d_in[5];
  const float* Wq = (const float*)d_in[6];  const float* bq = (const float*)d_in[7];
  const float* Wv = (const float*)d_in[8];  const float* bv = (const float*)d_in[9];
  const float* Wp = (const float*)d_in[10]; const float* bp = (const float*)d_in[11];
  float* out = (float*)d_out;

  char* ws = (char*)d_ws;
  short* wbf = (short*)ws;  // 4 x 512x512 bf16 = 2 MB
  size_t off = (size_t)4 * 262144 * 2;
  float* rpbL = (float*)(ws + off); off += (size_t)16 * 4096 * 4;     // 256 KB
  float* maskL = (float*)(ws + off); off += (size_t)1024 * 4096 * 4;  // 16 MB

  const size_t perw = 2 * 49 * 1024 + 2 * 50176 + 65536;  // 266240 B/window
  size_t avail = (ws_size > off + 65536) ? ws_size - off - 65536 : 0;
  int CH = (int)((avail > 300000) ? (avail - 262144) / perw : 1);
  if (CH > 4096) CH = 4096;
  if (CH < 1) CH = 1;
  const int RWS = ((CH * 49 + 127) / 128) * 128;

  short* Al = (short*)(ws + off); off += (size_t)RWS * 1024;
  short* Ag = (short*)(ws + off); off += (size_t)RWS * 1024;
  bf16* q_ws = (bf16*)(ws + off); off += (size_t)CH * 50176;
  bf16* k_ws = (bf16*)(ws + off); off += (size_t)CH * 50176;
  bf16* vT_ws = (bf16*)(ws + off); off += (size_t)CH * 65536;
  bf16* x_ws = (bf16*)Al;  // alias: Al dead after gemm_kqv

  cvt_w_kernel<<<256, 256, 0, stream>>>(Wk, Wq, Wv, Wp, (bf16*)wbf);
  prep_rpbL<<<64, 256, 0, stream>>>(btab, rpbL);
  prep_maskL<<<4096, 256, 0, stream>>>(mask, maskL);

  const float qscale = 0.17677669529663687f;  // 1/sqrt(32)
  for (int wstart = 0; wstart < 4096; wstart += CH) {
    const int nwin = (4096 - wstart < CH) ? (4096 - wstart) : CH;
    const int M = nwin * 49;
    const int gy = (M + 127) / 128;
    const int cg = (M * 64 + 255) / 256;
    cvt_a<<<cg, 256, 0, stream>>>(lf + (size_t)wstart * 25088, Al, M);
    cvt_a<<<cg, 256, 0, stream>>>(gfx + (size_t)wstart * 25088, Ag, M);
    gemm_kqv<<<6 * gy, 512, 0, stream>>>(Al, Ag, wbf, bk, bq, bv, qscale,
                                         k_ws, q_ws, vT_ws, M);
    attn_win3<<<dim3(nwin, 2), 512, 0, stream>>>(q_ws, k_ws, vT_ws, rpbL,
                                                 maskL, x_ws, wstart);
    gemm_p<<<2 * gy, 512, 0, stream>>>((const short*)x_ws, wbf + 3 * 262144,
                                       bp, out + (size_t)wstart * 25088, M);
  }
}

// Round 13
// 1271.887 us; speedup vs baseline: 1.0385x; 1.0084x over previous
//
#include <hip/hip_runtime.h>
#include <hip/hip_bf16.h>

typedef __hip_bfloat16 bf16;
typedef __attribute__((ext_vector_type(4))) float f32x4;
typedef __attribute__((ext_vector_type(8))) short short8;
typedef __attribute__((ext_vector_type(4))) short short4v;

#define NEGBIG (-3.0e38f)

__device__ __forceinline__ unsigned short f2b(float x) {
  union { float f; unsigned int u; } v; v.f = x;
  unsigned int r = v.u + 0x7fffu + ((v.u >> 16) & 1u);
  return (unsigned short)(r >> 16);
}

__device__ __forceinline__ void gl16(const void* g, void* l) {
  __builtin_amdgcn_global_load_lds(
      (const __attribute__((address_space(1))) unsigned int*)g,
      (__attribute__((address_space(3))) unsigned int*)l, 16, 0, 0);
}

// bijective XCD-grouping swizzle (m204): contiguous tile range per XCD
__device__ __forceinline__ int xcd_swz(int orig, int nwg) {
  const int q = nwg >> 3, r = nwg & 7;
  const int xcd = orig & 7;
  const int base = (xcd < r) ? xcd * (q + 1) : r * (q + 1) + (xcd - r) * q;
  return base + (orig >> 3);
}

// ---------------- weight f32 -> bf16 (row-major) ----------------
__global__ __launch_bounds__(256) void cvt_w_kernel(
    const float* __restrict__ a, const float* __restrict__ b,
    const float* __restrict__ c, const float* __restrict__ d,
    bf16* __restrict__ dst) {
  const int t = blockIdx.x * 256 + threadIdx.x;
  const float* srcs[4] = {a, b, c, d};
#pragma unroll
  for (int w = 0; w < 4; ++w) {
    const f32x4 v = *(const f32x4*)(srcs[w] + (size_t)t * 4);
    short4v o;
    o[0] = (short)f2b(v[0]); o[1] = (short)f2b(v[1]);
    o[2] = (short)f2b(v[2]); o[3] = (short)f2b(v[3]);
    *(short4v*)((short*)dst + (size_t)w * 262144 + (size_t)t * 4) = o;
  }
}

// ---------------- activation f32 -> bf16 (row-major [M][512]) -------------
__global__ __launch_bounds__(256) void cvt_a(const float* __restrict__ src,
                                             short* __restrict__ dst, int M) {
  const int g = blockIdx.x * 256 + threadIdx.x;
  const int row = g >> 6, k8 = g & 63;
  if (row >= M) return;
  const float* sp = src + (size_t)row * 512 + k8 * 8;
  const f32x4 lo = *(const f32x4*)sp;
  const f32x4 hi = *(const f32x4*)(sp + 4);
  short8 u;
  u[0] = (short)f2b(lo[0]); u[1] = (short)f2b(lo[1]);
  u[2] = (short)f2b(lo[2]); u[3] = (short)f2b(lo[3]);
  u[4] = (short)f2b(hi[0]); u[5] = (short)f2b(hi[1]);
  u[6] = (short)f2b(hi[2]); u[7] = (short)f2b(hi[3]);
  *(short8*)(dst + (size_t)row * 512 + k8 * 8) = u;
}

// ---- bias table -> per-(head, frag-element) layout, pads = NEGBIG ----
__global__ __launch_bounds__(256) void prep_rpbL(const float* __restrict__ btab,
                                                 float* __restrict__ rpbL) {
  const int g = blockIdx.x * 256 + threadIdx.x;
  const int lane = g & 63, mn = (g >> 6) & 15, h = g >> 10;
  const int m = mn >> 2, n = mn & 3, l15 = lane & 15, lg = lane >> 4;
  const int cc = n * 16 + l15;
  const int aj = cc / 7, bj = cc % 7;
  f32x4 o;
#pragma unroll
  for (int reg = 0; reg < 4; ++reg) {
    const int i = m * 16 + lg * 4 + reg;
    if (i < 49 && cc < 49) {
      const int t = (i / 7 - aj + 6) * 13 + (i % 7 - bj + 6);
      o[reg] = btab[t * 16 + h];
    } else {
      o[reg] = NEGBIG;
    }
  }
  ((f32x4*)rpbL)[g] = o;
}

// ---- mask -> per-(window, frag-element) layout, pads = 0 ----
__global__ __launch_bounds__(256) void prep_maskL(const float* __restrict__ mask,
                                                  float* __restrict__ maskL) {
  const int g = blockIdx.x * 256 + threadIdx.x;
  const int lane = g & 63, mn = (g >> 6) & 15, wm = g >> 10;
  const int m = mn >> 2, n = mn & 3, l15 = lane & 15, lg = lane >> 4;
  const int cc = n * 16 + l15;
  f32x4 o;
#pragma unroll
  for (int reg = 0; reg < 4; ++reg) {
    const int i = m * 16 + lg * 4 + reg;
    o[reg] = (i < 49 && cc < 49) ? mask[(size_t)wm * 2401 + i * 49 + cc] : 0.f;
  }
  ((f32x4*)maskL)[g] = o;
}

// ------- m97-geometry staging: A 128x64 (16KB), B 256x64 (32KB), swizzled ----
// LDS dest linear (gl16 rule); global 16B-slot col c is fetched from c^(row&7)
// so the XOR'd ds_read below is conflict-free (rule #21).
__device__ __forceinline__ void stage_m97(const char* Ab, const char* Bb,
                                          char* As, char* Bs, int arow0,
                                          int brow0, int k0) {
  const int tid = threadIdx.x;  // 512 threads
#pragma unroll
  for (int i = 0; i < 2; ++i) {
    const int s = tid + 512 * i;  // A: 1024 slots of 16B
    const int row = s >> 3;
    const int sc = (s & 7) ^ (row & 7);
    gl16(Ab + (size_t)(arow0 + row) * 1024 + k0 * 2 + sc * 16, As + s * 16);
  }
#pragma unroll
  for (int i = 0; i < 4; ++i) {
    const int s = tid + 512 * i;  // B: 2048 slots of 16B
    const int row = s >> 3;
    const int sc = (s & 7) ^ (row & 7);
    gl16(Bb + (size_t)(brow0 + row) * 1024 + k0 * 2 + sc * 16, Bs + s * 16);
  }
}

// ---------------- fused KQV GEMM, m97 geometry ------------------------------
// grid 6*gy, XCD-swizzled; bn%6: cls = bn>>1 (0=K,1=Q,2=V^T), bnl = bn&1.
// BM=128 (tokens), BN=256 (channels), BK=64, 8 waves, single-buffer 48KB LDS
// -> 3 blocks/CU (24 waves). V^T via operand swap + remapped wave grid.
__global__ __launch_bounds__(512, 4) void gemm_kqv(
    const short* __restrict__ Al, const short* __restrict__ Ag,
    const short* __restrict__ wbf, const float* __restrict__ bk,
    const float* __restrict__ bq, const float* __restrict__ bv, float qscale,
    bf16* __restrict__ k_ws, bf16* __restrict__ q_ws, bf16* __restrict__ vT_ws,
    int M) {
  __shared__ char lds[49152];
  char* As = lds;           // [128][128B]
  char* Bs = lds + 16384;   // [256][128B]
  const int nwg = gridDim.x;
  const int t0 = xcd_swz(blockIdx.x, nwg);
  const int bn = t0 % 6, bm = t0 / 6;
  const int cls = bn >> 1, bnl = bn & 1;
  const int tid = threadIdx.x, lane = tid & 63, wid = tid >> 6;
  const int l15 = lane & 15, lg = lane >> 4;
  const bool swap = (cls == 2);
  // normal: wr (2) x wc (4); swap: cm (4, channels) x ct (2, tokens)
  const int wr = swap ? (wid & 3) : (wid >> 2);
  const int wc = swap ? (wid >> 2) : (wid & 3);
  const char* Ab = (const char*)((cls == 1) ? Ag : Al);
  const char* Bb = (const char*)(wbf + (size_t)cls * 262144);

  f32x4 acc[4][4];
#pragma unroll
  for (int m = 0; m < 4; ++m)
#pragma unroll
    for (int n = 0; n < 4; ++n) acc[m][n] = (f32x4){0.f, 0.f, 0.f, 0.f};

  const char* fam = swap ? Bs : As;  // A-operand source (m-axis rows)
  const char* fbm = swap ? As : Bs;  // B-operand source (n-axis rows)

  for (int kt = 0; kt < 8; ++kt) {
    stage_m97(Ab, Bb, As, Bs, bm * 128, bnl * 256, kt * 64);
    __syncthreads();
#pragma unroll
    for (int s = 0; s < 2; ++s) {
      short8 af[4], bfr[4];
#pragma unroll
      for (int m = 0; m < 4; ++m) {
        const int r = wr * 64 + m * 16 + l15;
        af[m] = *(const short8*)(fam + r * 128 +
                                 (((s * 4 + lg) ^ (r & 7)) << 4));
      }
#pragma unroll
      for (int n = 0; n < 4; ++n) {
        const int r = wc * 64 + n * 16 + l15;
        bfr[n] = *(const short8*)(fbm + r * 128 +
                                  (((s * 4 + lg) ^ (r & 7)) << 4));
      }
#pragma unroll
      for (int m = 0; m < 4; ++m)
#pragma unroll
        for (int n = 0; n < 4; ++n)
          acc[m][n] = __builtin_amdgcn_mfma_f32_16x16x32_bf16(
              af[m], bfr[n], acc[m][n], 0, 0, 0);
    }
    __syncthreads();
  }

  if (cls == 2) {  // V^T: m-axis = channels (256), n-axis = tokens (128)
#pragma unroll
    for (int m = 0; m < 4; ++m) {
#pragma unroll
      for (int n = 0; n < 4; ++n) {
        const int tok = bm * 128 + wc * 64 + n * 16 + l15;
        if (tok < M) {
          const int w = tok / 49, nt = tok - w * 49;
#pragma unroll
          for (int reg = 0; reg < 4; ++reg) {
            const int ch = bnl * 256 + wr * 64 + m * 16 + lg * 4 + reg;
            const float v = acc[m][n][reg] + bv[ch];
            const int hh = ch >> 5, dd = ch & 31;
            vT_ws[(((size_t)w * 16 + hh) * 32 + dd) * 64 + nt] =
                __float2bfloat16(v);
          }
        }
      }
    }
  } else {
    const float* bb = (cls == 0) ? bk : bq;
    bf16* dp = (cls == 0) ? k_ws : q_ws;
    const float sc = (cls == 0) ? 1.0f : qscale;
#pragma unroll
    for (int m = 0; m < 4; ++m) {
#pragma unroll
      for (int n = 0; n < 4; ++n) {
        const int c = bnl * 256 + wc * 64 + n * 16 + l15;
        const float bvv = bb[c];
        const int hh = c >> 5, dd = c & 31;
#pragma unroll
        for (int reg = 0; reg < 4; ++reg) {
          const int r = bm * 128 + wr * 64 + m * 16 + lg * 4 + reg;
          if (r < M) {
            const int w = r / 49, nt = r - w * 49;
            dp[(((size_t)w * 16 + hh) * 49 + nt) * 32 + dd] =
                __float2bfloat16((acc[m][n][reg] + bvv) * sc);
          }
        }
      }
    }
  }
}

// ---------------- proj GEMM, m97 geometry: f32 out [r][512] -----------------
__global__ __launch_bounds__(512, 4) void gemm_p(const short* __restrict__ Abf,
                                                 const short* __restrict__ Bbf,
                                                 const float* __restrict__ bias,
                                                 float* __restrict__ dst,
                                                 int M) {
  __shared__ char lds[49152];
  char* As = lds;
  char* Bs = lds + 16384;
  const int nwg = gridDim.x;
  const int t0 = xcd_swz(blockIdx.x, nwg);
  const int bnl = t0 & 1, bm = t0 >> 1;
  const int tid = threadIdx.x, lane = tid & 63, wid = tid >> 6;
  const int wr = wid >> 2, wc = wid & 3, l15 = lane & 15, lg = lane >> 4;

  f32x4 acc[4][4];
#pragma unroll
  for (int m = 0; m < 4; ++m)
#pragma unroll
    for (int n = 0; n < 4; ++n) acc[m][n] = (f32x4){0.f, 0.f, 0.f, 0.f};

  for (int kt = 0; kt < 8; ++kt) {
    stage_m97((const char*)Abf, (const char*)Bbf, As, Bs, bm * 128, bnl * 256,
              kt * 64);
    __syncthreads();
#pragma unroll
    for (int s = 0; s < 2; ++s) {
      short8 af[4], bfr[4];
#pragma unroll
      for (int m = 0; m < 4; ++m) {
        const int r = wr * 64 + m * 16 + l15;
        af[m] = *(const short8*)(As + r * 128 +
                                 (((s * 4 + lg) ^ (r & 7)) << 4));
      }
#pragma unroll
      for (int n = 0; n < 4; ++n) {
        const int r = wc * 64 + n * 16 + l15;
        bfr[n] = *(const short8*)(Bs + r * 128 +
                                  (((s * 4 + lg) ^ (r & 7)) << 4));
      }
#pragma unroll
      for (int m = 0; m < 4; ++m)
#pragma unroll
        for (int n = 0; n < 4; ++n)
          acc[m][n] = __builtin_amdgcn_mfma_f32_16x16x32_bf16(
              af[m], bfr[n], acc[m][n], 0, 0, 0);
    }
    __syncthreads();
  }

#pragma unroll
  for (int m = 0; m < 4; ++m) {
#pragma unroll
    for (int n = 0; n < 4; ++n) {
      const int c = bnl * 256 + wc * 64 + n * 16 + l15;
      const float bvv = bias[c];
#pragma unroll
      for (int reg = 0; reg < 4; ++reg) {
        const int r = bm * 128 + wr * 64 + m * 16 + lg * 4 + reg;
        if (r < M) dst[(size_t)r * 512 + c] = acc[m][n][reg] + bvv;
      }
    }
  }
}

// ---------------- windowed attention: 1 head per wave, no barriers ---------
__global__ __launch_bounds__(256) void attn_win2(
    const bf16* __restrict__ q_ws, const bf16* __restrict__ k_ws,
    const bf16* __restrict__ vT_ws, const float* __restrict__ rpbL,
    const float* __restrict__ maskL, bf16* __restrict__ x_ws, int wstart) {
  __shared__ short sP[4][4096];
  const int tid = threadIdx.x, lane = tid & 63, wid = tid >> 6;
  const int l15 = lane & 15, lg = lane >> 4;
  const int wl = blockIdx.x;
  const int h = blockIdx.y * 4 + wid;
  const int wg = wstart + wl;
  char* Pl = (char*)sP[wid];
  const size_t base = ((size_t)wl * 16 + h) * 1568;
  const short8 z8 = (short8){0, 0, 0, 0, 0, 0, 0, 0};

  short8 qf[4], kf[4];
#pragma unroll
  for (int m = 0; m < 4; ++m) {
    const int r = m * 16 + l15;
    qf[m] = (r < 49) ? *(const short8*)(q_ws + base + r * 32 + lg * 8) : z8;
    kf[m] = (r < 49) ? *(const short8*)(k_ws + base + r * 32 + lg * 8) : z8;
  }
  f32x4 lc[4][4];
#pragma unroll
  for (int m = 0; m < 4; ++m)
#pragma unroll
    for (int n = 0; n < 4; ++n)
      lc[m][n] = __builtin_amdgcn_mfma_f32_16x16x32_bf16(
          qf[m], kf[n], (f32x4){0.f, 0.f, 0.f, 0.f}, 0, 0, 0);

  const f32x4* rbp = (const f32x4*)rpbL + (size_t)h * 1024 + lane;
  const f32x4* mkp = (const f32x4*)maskL + (size_t)(wg & 1023) * 1024 + lane;
#pragma unroll
  for (int m = 0; m < 4; ++m)
#pragma unroll
    for (int n = 0; n < 4; ++n) {
      const int mn = m * 4 + n;
      lc[m][n] += rbp[mn * 64] + mkp[mn * 64];
    }

#pragma unroll
  for (int m = 0; m < 4; ++m) {
#pragma unroll
    for (int reg = 0; reg < 4; ++reg) {
      float vmax = fmaxf(fmaxf(lc[m][0][reg], lc[m][1][reg]),
                         fmaxf(lc[m][2][reg], lc[m][3][reg]));
#pragma unroll
      for (int off = 1; off < 16; off <<= 1)
        vmax = fmaxf(vmax, __shfl_xor(vmax, off, 64));
      float e[4], ssum = 0.f;
#pragma unroll
      for (int n = 0; n < 4; ++n) {
        e[n] = __expf(lc[m][n][reg] - vmax);
        ssum += e[n];
      }
#pragma unroll
      for (int off = 1; off < 16; off <<= 1) ssum += __shfl_xor(ssum, off, 64);
      const float inv = __builtin_amdgcn_rcpf(ssum);
      const int i = m * 16 + lg * 4 + reg;
#pragma unroll
      for (int n = 0; n < 4; ++n) {
        const int cc = n * 16 + l15;
        *(unsigned short*)(Pl + i * 128 + ((2 * cc) ^ ((i & 7) << 4))) =
            f2b(e[n] * inv);
      }
    }
  }

  f32x4 xacc[4][2];
#pragma unroll
  for (int m = 0; m < 4; ++m)
#pragma unroll
    for (int n = 0; n < 2; ++n) xacc[m][n] = (f32x4){0.f, 0.f, 0.f, 0.f};
  const size_t vbase = ((size_t)wl * 16 + h) * 2048;
#pragma unroll
  for (int s = 0; s < 2; ++s) {
    short8 pf[4], vf[2];
#pragma unroll
    for (int m = 0; m < 4; ++m) {
      const int i = m * 16 + l15;
      pf[m] = *(const short8*)(Pl + i * 128 +
                               ((s * 64 + lg * 16) ^ ((i & 7) << 4)));
    }
#pragma unroll
    for (int n = 0; n < 2; ++n) {
      const int dd = n * 16 + l15;
      short8 vv = *(const short8*)(vT_ws + vbase + dd * 64 + s * 32 + lg * 8);
      if (s == 1) {
        if (lg == 3) vv = z8;
        else if (lg == 2) {
          vv[1] = 0; vv[2] = 0; vv[3] = 0; vv[4] = 0;
          vv[5] = 0; vv[6] = 0; vv[7] = 0;
        }
      }
      vf[n] = vv;
    }
#pragma unroll
    for (int m = 0; m < 4; ++m)
#pragma unroll
      for (int n = 0; n < 2; ++n)
        xacc[m][n] = __builtin_amdgcn_mfma_f32_16x16x32_bf16(
            pf[m], vf[n], xacc[m][n], 0, 0, 0);
  }

#pragma unroll
  for (int m = 0; m < 4; ++m)
#pragma unroll
    for (int n = 0; n < 2; ++n)
#pragma unroll
      for (int reg = 0; reg < 4; ++reg) {
        const int i = m * 16 + lg * 4 + reg;
        const int dd = n * 16 + l15;
        *(unsigned short*)(Pl + i * 80 + ((2 * dd) ^ ((i & 3) << 4))) =
            f2b(xacc[m][n][reg]);
      }
#pragma unroll
  for (int g = 0; g < 4; ++g) {
    const int row = g * 16 + (lane >> 2);
    if (row < 49) {
      const short8 xv = *(const short8*)(
          Pl + row * 80 + (((lane & 3) * 16) ^ ((row & 3) << 4)));
      *(short8*)(x_ws + ((size_t)wl * 49 + row) * 512 + h * 32 +
                 (lane & 3) * 8) = xv;
    }
  }
}

extern "C" void kernel_launch(void* const* d_in, const int* in_sizes, int n_in,
                              void* d_out, int out_size, void* d_ws,
                              size_t ws_size, hipStream_t stream) {
  const float* lf   = (const float*)d_in[0];
  const float* gfx  = (const float*)d_in[1];
  const float* mask = (const float*)d_in[2];
  const float* btab = (const float*)d_in[3];
  const float* Wk = (const float*)d_in[4];  const float* bk = (const float*)d_in[5];
  const float* Wq = (const float*)d_in[6];  const float* bq = (const float*)d_in[7];
  const float* Wv = (const float*)d_in[8];  const float* bv = (const float*)d_in[9];
  const float* Wp = (const float*)d_in[10]; const float* bp = (const float*)d_in[11];
  float* out = (float*)d_out;

  char* ws = (char*)d_ws;
  short* wbf = (short*)ws;  // 4 x 512x512 bf16 = 2 MB
  size_t off = (size_t)4 * 262144 * 2;
  float* rpbL = (float*)(ws + off); off += (size_t)16 * 4096 * 4;     // 256 KB
  float* maskL = (float*)(ws + off); off += (size_t)1024 * 4096 * 4;  // 16 MB

  const size_t perw = 2 * 49 * 1024 + 2 * 50176 + 65536;  // 266240 B/window
  size_t avail = (ws_size > off + 65536) ? ws_size - off - 65536 : 0;
  int CH = (int)((avail > 300000) ? (avail - 262144) / perw : 1);
  if (CH > 4096) CH = 4096;
  if (CH < 1) CH = 1;
  const int RWS = ((CH * 49 + 127) / 128) * 128;

  short* Al = (short*)(ws + off); off += (size_t)RWS * 1024;
  short* Ag = (short*)(ws + off); off += (size_t)RWS * 1024;
  bf16* q_ws = (bf16*)(ws + off); off += (size_t)CH * 50176;
  bf16* k_ws = (bf16*)(ws + off); off += (size_t)CH * 50176;
  bf16* vT_ws = (bf16*)(ws + off); off += (size_t)CH * 65536;
  bf16* x_ws = (bf16*)Al;  // alias: Al dead after gemm_kqv

  cvt_w_kernel<<<256, 256, 0, stream>>>(Wk, Wq, Wv, Wp, (bf16*)wbf);
  prep_rpbL<<<64, 256, 0, stream>>>(btab, rpbL);
  prep_maskL<<<4096, 256, 0, stream>>>(mask, maskL);

  const float qscale = 0.17677669529663687f;  // 1/sqrt(32)
  for (int wstart = 0; wstart < 4096; wstart += CH) {
    const int nwin = (4096 - wstart < CH) ? (4096 - wstart) : CH;
    const int M = nwin * 49;
    const int gy = (M + 127) / 128;
    const int cg = (M * 64 + 255) / 256;
    cvt_a<<<cg, 256, 0, stream>>>(lf + (size_t)wstart * 25088, Al, M);
    cvt_a<<<cg, 256, 0, stream>>>(gfx + (size_t)wstart * 25088, Ag, M);
    gemm_kqv<<<6 * gy, 512, 0, stream>>>(Al, Ag, wbf, bk, bq, bv, qscale,
                                         k_ws, q_ws, vT_ws, M);
    attn_win2<<<dim3(nwin, 4), 256, 0, stream>>>(q_ws, k_ws, vT_ws, rpbL,
                                                 maskL, x_ws, wstart);
    gemm_p<<<2 * gy, 512, 0, stream>>>((const short*)x_ws, wbf + 3 * 262144,
                                       bp, out + (size_t)wstart * 25088, M);
  }
}

// Round 14
// 1160.856 us; speedup vs baseline: 1.1379x; 1.0956x over previous
//
#include <hip/hip_runtime.h>
#include <hip/hip_bf16.h>

typedef __hip_bfloat16 bf16;
typedef __attribute__((ext_vector_type(4))) float f32x4;
typedef __attribute__((ext_vector_type(8))) short short8;
typedef __attribute__((ext_vector_type(4))) short short4v;

#define NEGBIG (-3.0e38f)

__device__ __forceinline__ unsigned short f2b(float x) {
  union { float f; unsigned int u; } v; v.f = x;
  unsigned int r = v.u + 0x7fffu + ((v.u >> 16) & 1u);
  return (unsigned short)(r >> 16);
}

__device__ __forceinline__ void gl16(const void* g, void* l) {
  __builtin_amdgcn_global_load_lds(
      (const __attribute__((address_space(1))) unsigned int*)g,
      (__attribute__((address_space(3))) unsigned int*)l, 16, 0, 0);
}

// bijective XCD-grouping swizzle (m204): contiguous tile range per XCD
__device__ __forceinline__ int xcd_swz(int orig, int nwg) {
  const int q = nwg >> 3, r = nwg & 7;
  const int xcd = orig & 7;
  const int base = (xcd < r) ? xcd * (q + 1) : r * (q + 1) + (xcd - r) * q;
  return base + (orig >> 3);
}

// ---------------- weight f32 -> bf16 (row-major) ----------------
__global__ __launch_bounds__(256) void cvt_w_kernel(
    const float* __restrict__ a, const float* __restrict__ b,
    const float* __restrict__ c, const float* __restrict__ d,
    bf16* __restrict__ dst) {
  const int t = blockIdx.x * 256 + threadIdx.x;
  const float* srcs[4] = {a, b, c, d};
#pragma unroll
  for (int w = 0; w < 4; ++w) {
    const f32x4 v = *(const f32x4*)(srcs[w] + (size_t)t * 4);
    short4v o;
    o[0] = (short)f2b(v[0]); o[1] = (short)f2b(v[1]);
    o[2] = (short)f2b(v[2]); o[3] = (short)f2b(v[3]);
    *(short4v*)((short*)dst + (size_t)w * 262144 + (size_t)t * 4) = o;
  }
}

// ---- bias table -> per-(head, frag-element) layout, pads = NEGBIG ----
__global__ __launch_bounds__(256) void prep_rpbL(const float* __restrict__ btab,
                                                 float* __restrict__ rpbL) {
  const int g = blockIdx.x * 256 + threadIdx.x;
  const int lane = g & 63, mn = (g >> 6) & 15, h = g >> 10;
  const int m = mn >> 2, n = mn & 3, l15 = lane & 15, lg = lane >> 4;
  const int cc = n * 16 + l15;
  const int aj = cc / 7, bj = cc % 7;
  f32x4 o;
#pragma unroll
  for (int reg = 0; reg < 4; ++reg) {
    const int i = m * 16 + lg * 4 + reg;
    if (i < 49 && cc < 49) {
      const int t = (i / 7 - aj + 6) * 13 + (i % 7 - bj + 6);
      o[reg] = btab[t * 16 + h];
    } else {
      o[reg] = NEGBIG;
    }
  }
  ((f32x4*)rpbL)[g] = o;
}

// ---- mask -> per-(window, frag-element) layout, pads = 0 ----
__global__ __launch_bounds__(256) void prep_maskL(const float* __restrict__ mask,
                                                  float* __restrict__ maskL) {
  const int g = blockIdx.x * 256 + threadIdx.x;
  const int lane = g & 63, mn = (g >> 6) & 15, wm = g >> 10;
  const int m = mn >> 2, n = mn & 3, l15 = lane & 15, lg = lane >> 4;
  const int cc = n * 16 + l15;
  f32x4 o;
#pragma unroll
  for (int reg = 0; reg < 4; ++reg) {
    const int i = m * 16 + lg * 4 + reg;
    o[reg] = (i < 49 && cc < 49) ? mask[(size_t)wm * 2401 + i * 49 + cc] : 0.f;
  }
  ((f32x4*)maskL)[g] = o;
}

// ---------------- fused KQV GEMM, m97 geometry, f32-A in-LDS convert --------
// grid 6*gy, XCD-swizzled; bn%6: cls = bn>>1 (0=K,1=Q,2=V^T), bnl = bn&1.
// BM=128 (tokens), BN=256 (channels), BK=64, 8 waves. LDS (80KB, 2 blk/CU):
//   Af32 [0,32K): 128x64 f32, linear (gl16 direct from f32 activations)
//   Abf  [32K,48K): 128x64 bf16, R8 layout/swizzle (written by convert phase)
//   Bs   [48K,80K): 256x64 bf16, R8 layout/swizzle (gl16 from bf16 weights)
// Per K-step: stage(gl16) -> bar -> LDS convert (b128 read, cvt_pk RNE,
// b64 write) -> bar -> R8-identical ds_read+32 MFMA -> bar.
__global__ __launch_bounds__(512, 4) void gemm_kqv(
    const float* __restrict__ lf, const float* __restrict__ gfx,
    const short* __restrict__ wbf, const float* __restrict__ bk,
    const float* __restrict__ bq, const float* __restrict__ bv, float qscale,
    bf16* __restrict__ k_ws, bf16* __restrict__ q_ws, bf16* __restrict__ vT_ws,
    int M) {
  __shared__ char lds[81920];
  char* Af32 = lds;           // 32 KB
  char* Abf = lds + 32768;    // 16 KB
  char* Bs = lds + 49152;     // 32 KB
  const int nwg = gridDim.x;
  const int t0 = xcd_swz(blockIdx.x, nwg);
  const int bn = t0 % 6, bm = t0 / 6;
  const int cls = bn >> 1, bnl = bn & 1;
  const int tid = threadIdx.x, lane = tid & 63, wid = tid >> 6;
  const int l15 = lane & 15, lg = lane >> 4;
  const bool swap = (cls == 2);
  // normal: wr (2) x wc (4); swap: cm (4, channels) x ct (2, tokens)
  const int wr = swap ? (wid & 3) : (wid >> 2);
  const int wc = swap ? (wid >> 2) : (wid & 3);
  const float* Af = (cls == 1) ? gfx : lf;
  const char* Bb = (const char*)(wbf + (size_t)cls * 262144);

  f32x4 acc[4][4];
#pragma unroll
  for (int m = 0; m < 4; ++m)
#pragma unroll
    for (int n = 0; n < 4; ++n) acc[m][n] = (f32x4){0.f, 0.f, 0.f, 0.f};

  const char* fam = swap ? Bs : Abf;  // A-operand source (m-axis rows)
  const char* fbm = swap ? Abf : Bs;  // B-operand source (n-axis rows)

  // convert-phase constants (thread t covers f32 slot col tid&15 of rows
  // crow0 + {0,32,64,96})
  const int crow0 = tid >> 4;
  const int ccol = tid & 15;
  const int c4 = ccol >> 1, hh8 = (ccol & 1) * 8;

  for (int kt = 0; kt < 8; ++kt) {
    const int k0 = kt * 64;
    // ---- stage: A f32 (2048 slots of 16B, linear dest) ----
#pragma unroll
    for (int i = 0; i < 4; ++i) {
      const int s = tid + 512 * i;
      const int row = s >> 4, col = s & 15;
      int gr = bm * 128 + row;
      if (gr >= M) gr = M - 1;  // clamp: keep source reads in-bounds
      gl16((const char*)Af + (size_t)gr * 2048 + k0 * 4 + col * 16,
           Af32 + s * 16);
    }
    // ---- stage: B bf16 (R8 swizzled source) ----
#pragma unroll
    for (int i = 0; i < 4; ++i) {
      const int s = tid + 512 * i;
      const int row = s >> 3;
      const int sc = (s & 7) ^ (row & 7);
      gl16(Bb + (size_t)(bnl * 256 + row) * 1024 + k0 * 2 + sc * 16,
           Bs + s * 16);
    }
    __syncthreads();  // Af32 + Bs resident

    // ---- convert: Af32 -> Abf (R8 layout: row*128 + ((c4^(row&7))<<4)) ----
#pragma unroll
    for (int j = 0; j < 4; ++j) {
      const int rj = crow0 + 32 * j;
      const f32x4 v = *(const f32x4*)(Af32 + (tid + 512 * j) * 16);
      unsigned int w0, w1;
      asm("v_cvt_pk_bf16_f32 %0, %1, %2" : "=v"(w0) : "v"(v[0]), "v"(v[1]));
      asm("v_cvt_pk_bf16_f32 %0, %1, %2" : "=v"(w1) : "v"(v[2]), "v"(v[3]));
      *(unsigned long long*)(Abf + rj * 128 + (((c4 ^ (rj & 7)) << 4) | hh8)) =
          ((unsigned long long)w1 << 32) | w0;
    }
    __syncthreads();  // Abf resident

    // ---- compute: R8-identical read path + MFMA ----
#pragma unroll
    for (int s = 0; s < 2; ++s) {
      short8 af[4], bfr[4];
#pragma unroll
      for (int m = 0; m < 4; ++m) {
        const int r = wr * 64 + m * 16 + l15;
        af[m] = *(const short8*)(fam + r * 128 +
                                 (((s * 4 + lg) ^ (r & 7)) << 4));
      }
#pragma unroll
      for (int n = 0; n < 4; ++n) {
        const int r = wc * 64 + n * 16 + l15;
        bfr[n] = *(const short8*)(fbm + r * 128 +
                                  (((s * 4 + lg) ^ (r & 7)) << 4));
      }
#pragma unroll
      for (int m = 0; m < 4; ++m)
#pragma unroll
        for (int n = 0; n < 4; ++n)
          acc[m][n] = __builtin_amdgcn_mfma_f32_16x16x32_bf16(
              af[m], bfr[n], acc[m][n], 0, 0, 0);
    }
    __syncthreads();  // all reads done before next stage
  }

  if (cls == 2) {  // V^T: m-axis = channels (256), n-axis = tokens (128)
#pragma unroll
    for (int m = 0; m < 4; ++m) {
#pragma unroll
      for (int n = 0; n < 4; ++n) {
        const int tok = bm * 128 + wc * 64 + n * 16 + l15;
        if (tok < M) {
          const int w = tok / 49, nt = tok - w * 49;
#pragma unroll
          for (int reg = 0; reg < 4; ++reg) {
            const int ch = bnl * 256 + wr * 64 + m * 16 + lg * 4 + reg;
            const float v = acc[m][n][reg] + bv[ch];
            const int hh = ch >> 5, dd = ch & 31;
            vT_ws[(((size_t)w * 16 + hh) * 32 + dd) * 64 + nt] =
                __float2bfloat16(v);
          }
        }
      }
    }
  } else {
    const float* bb = (cls == 0) ? bk : bq;
    bf16* dp = (cls == 0) ? k_ws : q_ws;
    const float sc = (cls == 0) ? 1.0f : qscale;
#pragma unroll
    for (int m = 0; m < 4; ++m) {
#pragma unroll
      for (int n = 0; n < 4; ++n) {
        const int c = bnl * 256 + wc * 64 + n * 16 + l15;
        const float bvv = bb[c];
        const int hh = c >> 5, dd = c & 31;
#pragma unroll
        for (int reg = 0; reg < 4; ++reg) {
          const int r = bm * 128 + wr * 64 + m * 16 + lg * 4 + reg;
          if (r < M) {
            const int w = r / 49, nt = r - w * 49;
            dp[(((size_t)w * 16 + hh) * 49 + nt) * 32 + dd] =
                __float2bfloat16((acc[m][n][reg] + bvv) * sc);
          }
        }
      }
    }
  }
}

// ------- m97-geometry staging (proj): A 128x64, B 256x64 bf16, swizzled -----
__device__ __forceinline__ void stage_m97(const char* Ab, const char* Bb,
                                          char* As, char* Bs, int arow0,
                                          int brow0, int k0) {
  const int tid = threadIdx.x;  // 512 threads
#pragma unroll
  for (int i = 0; i < 2; ++i) {
    const int s = tid + 512 * i;  // A: 1024 slots of 16B
    const int row = s >> 3;
    const int sc = (s & 7) ^ (row & 7);
    gl16(Ab + (size_t)(arow0 + row) * 1024 + k0 * 2 + sc * 16, As + s * 16);
  }
#pragma unroll
  for (int i = 0; i < 4; ++i) {
    const int s = tid + 512 * i;  // B: 2048 slots of 16B
    const int row = s >> 3;
    const int sc = (s & 7) ^ (row & 7);
    gl16(Bb + (size_t)(brow0 + row) * 1024 + k0 * 2 + sc * 16, Bs + s * 16);
  }
}

// ---------------- proj GEMM, m97 geometry: f32 out [r][512] -----------------
__global__ __launch_bounds__(512, 4) void gemm_p(const short* __restrict__ Abf,
                                                 const short* __restrict__ Bbf,
                                                 const float* __restrict__ bias,
                                                 float* __restrict__ dst,
                                                 int M) {
  __shared__ char lds[49152];
  char* As = lds;
  char* Bs = lds + 16384;
  const int nwg = gridDim.x;
  const int t0 = xcd_swz(blockIdx.x, nwg);
  const int bnl = t0 & 1, bm = t0 >> 1;
  const int tid = threadIdx.x, lane = tid & 63, wid = tid >> 6;
  const int wr = wid >> 2, wc = wid & 3, l15 = lane & 15, lg = lane >> 4;

  f32x4 acc[4][4];
#pragma unroll
  for (int m = 0; m < 4; ++m)
#pragma unroll
    for (int n = 0; n < 4; ++n) acc[m][n] = (f32x4){0.f, 0.f, 0.f, 0.f};

  for (int kt = 0; kt < 8; ++kt) {
    stage_m97((const char*)Abf, (const char*)Bbf, As, Bs, bm * 128, bnl * 256,
              kt * 64);
    __syncthreads();
#pragma unroll
    for (int s = 0; s < 2; ++s) {
      short8 af[4], bfr[4];
#pragma unroll
      for (int m = 0; m < 4; ++m) {
        const int r = wr * 64 + m * 16 + l15;
        af[m] = *(const short8*)(As + r * 128 +
                                 (((s * 4 + lg) ^ (r & 7)) << 4));
      }
#pragma unroll
      for (int n = 0; n < 4; ++n) {
        const int r = wc * 64 + n * 16 + l15;
        bfr[n] = *(const short8*)(Bs + r * 128 +
                                  (((s * 4 + lg) ^ (r & 7)) << 4));
      }
#pragma unroll
      for (int m = 0; m < 4; ++m)
#pragma unroll
        for (int n = 0; n < 4; ++n)
          acc[m][n] = __builtin_amdgcn_mfma_f32_16x16x32_bf16(
              af[m], bfr[n], acc[m][n], 0, 0, 0);
    }
    __syncthreads();
  }

#pragma unroll
  for (int m = 0; m < 4; ++m) {
#pragma unroll
    for (int n = 0; n < 4; ++n) {
      const int c = bnl * 256 + wc * 64 + n * 16 + l15;
      const float bvv = bias[c];
#pragma unroll
      for (int reg = 0; reg < 4; ++reg) {
        const int r = bm * 128 + wr * 64 + m * 16 + lg * 4 + reg;
        if (r < M) dst[(size_t)r * 512 + c] = acc[m][n][reg] + bvv;
      }
    }
  }
}

// ---------------- windowed attention: 1 head per wave, no barriers ---------
__global__ __launch_bounds__(256) void attn_win2(
    const bf16* __restrict__ q_ws, const bf16* __restrict__ k_ws,
    const bf16* __restrict__ vT_ws, const float* __restrict__ rpbL,
    const float* __restrict__ maskL, bf16* __restrict__ x_ws, int wstart) {
  __shared__ short sP[4][4096];
  const int tid = threadIdx.x, lane = tid & 63, wid = tid >> 6;
  const int l15 = lane & 15, lg = lane >> 4;
  const int wl = blockIdx.x;
  const int h = blockIdx.y * 4 + wid;
  const int wg = wstart + wl;
  char* Pl = (char*)sP[wid];
  const size_t base = ((size_t)wl * 16 + h) * 1568;
  const short8 z8 = (short8){0, 0, 0, 0, 0, 0, 0, 0};

  short8 qf[4], kf[4];
#pragma unroll
  for (int m = 0; m < 4; ++m) {
    const int r = m * 16 + l15;
    qf[m] = (r < 49) ? *(const short8*)(q_ws + base + r * 32 + lg * 8) : z8;
    kf[m] = (r < 49) ? *(const short8*)(k_ws + base + r * 32 + lg * 8) : z8;
  }
  f32x4 lc[4][4];
#pragma unroll
  for (int m = 0; m < 4; ++m)
#pragma unroll
    for (int n = 0; n < 4; ++n)
      lc[m][n] = __builtin_amdgcn_mfma_f32_16x16x32_bf16(
          qf[m], kf[n], (f32x4){0.f, 0.f, 0.f, 0.f}, 0, 0, 0);

  const f32x4* rbp = (const f32x4*)rpbL + (size_t)h * 1024 + lane;
  const f32x4* mkp = (const f32x4*)maskL + (size_t)(wg & 1023) * 1024 + lane;
#pragma unroll
  for (int m = 0; m < 4; ++m)
#pragma unroll
    for (int n = 0; n < 4; ++n) {
      const int mn = m * 4 + n;
      lc[m][n] += rbp[mn * 64] + mkp[mn * 64];
    }

#pragma unroll
  for (int m = 0; m < 4; ++m) {
#pragma unroll
    for (int reg = 0; reg < 4; ++reg) {
      float vmax = fmaxf(fmaxf(lc[m][0][reg], lc[m][1][reg]),
                         fmaxf(lc[m][2][reg], lc[m][3][reg]));
#pragma unroll
      for (int off = 1; off < 16; off <<= 1)
        vmax = fmaxf(vmax, __shfl_xor(vmax, off, 64));
      float e[4], ssum = 0.f;
#pragma unroll
      for (int n = 0; n < 4; ++n) {
        e[n] = __expf(lc[m][n][reg] - vmax);
        ssum += e[n];
      }
#pragma unroll
      for (int off = 1; off < 16; off <<= 1) ssum += __shfl_xor(ssum, off, 64);
      const float inv = __builtin_amdgcn_rcpf(ssum);
      const int i = m * 16 + lg * 4 + reg;
#pragma unroll
      for (int n = 0; n < 4; ++n) {
        const int cc = n * 16 + l15;
        *(unsigned short*)(Pl + i * 128 + ((2 * cc) ^ ((i & 7) << 4))) =
            f2b(e[n] * inv);
      }
    }
  }

  f32x4 xacc[4][2];
#pragma unroll
  for (int m = 0; m < 4; ++m)
#pragma unroll
    for (int n = 0; n < 2; ++n) xacc[m][n] = (f32x4){0.f, 0.f, 0.f, 0.f};
  const size_t vbase = ((size_t)wl * 16 + h) * 2048;
#pragma unroll
  for (int s = 0; s < 2; ++s) {
    short8 pf[4], vf[2];
#pragma unroll
    for (int m = 0; m < 4; ++m) {
      const int i = m * 16 + l15;
      pf[m] = *(const short8*)(Pl + i * 128 +
                               ((s * 64 + lg * 16) ^ ((i & 7) << 4)));
    }
#pragma unroll
    for (int n = 0; n < 2; ++n) {
      const int dd = n * 16 + l15;
      short8 vv = *(const short8*)(vT_ws + vbase + dd * 64 + s * 32 + lg * 8);
      if (s == 1) {
        if (lg == 3) vv = z8;
        else if (lg == 2) {
          vv[1] = 0; vv[2] = 0; vv[3] = 0; vv[4] = 0;
          vv[5] = 0; vv[6] = 0; vv[7] = 0;
        }
      }
      vf[n] = vv;
    }
#pragma unroll
    for (int m = 0; m < 4; ++m)
#pragma unroll
      for (int n = 0; n < 2; ++n)
        xacc[m][n] = __builtin_amdgcn_mfma_f32_16x16x32_bf16(
            pf[m], vf[n], xacc[m][n], 0, 0, 0);
  }

#pragma unroll
  for (int m = 0; m < 4; ++m)
#pragma unroll
    for (int n = 0; n < 2; ++n)
#pragma unroll
      for (int reg = 0; reg < 4; ++reg) {
        const int i = m * 16 + lg * 4 + reg;
        const int dd = n * 16 + l15;
        *(unsigned short*)(Pl + i * 80 + ((2 * dd) ^ ((i & 3) << 4))) =
            f2b(xacc[m][n][reg]);
      }
#pragma unroll
  for (int g = 0; g < 4; ++g) {
    const int row = g * 16 + (lane >> 2);
    if (row < 49) {
      const short8 xv = *(const short8*)(
          Pl + row * 80 + (((lane & 3) * 16) ^ ((row & 3) << 4)));
      *(short8*)(x_ws + ((size_t)wl * 49 + row) * 512 + h * 32 +
                 (lane & 3) * 8) = xv;
    }
  }
}

extern "C" void kernel_launch(void* const* d_in, const int* in_sizes, int n_in,
                              void* d_out, int out_size, void* d_ws,
                              size_t ws_size, hipStream_t stream) {
  const float* lf   = (const float*)d_in[0];
  const float* gfx  = (const float*)d_in[1];
  const float* mask = (const float*)d_in[2];
  const float* btab = (const float*)d_in[3];
  const float* Wk = (const float*)d_in[4];  const float* bk = (const float*)d_in[5];
  const float* Wq = (const float*)d_in[6];  const float* bq = (const float*)d_in[7];
  const float* Wv = (const float*)d_in[8];  const float* bv = (const float*)d_in[9];
  const float* Wp = (const float*)d_in[10]; const float* bp = (const float*)d_in[11];
  float* out = (float*)d_out;

  char* ws = (char*)d_ws;
  short* wbf = (short*)ws;  // 4 x 512x512 bf16 = 2 MB
  size_t off = (size_t)4 * 262144 * 2;
  float* rpbL = (float*)(ws + off); off += (size_t)16 * 4096 * 4;     // 256 KB
  float* maskL = (float*)(ws + off); off += (size_t)1024 * 4096 * 4;  // 16 MB

  const size_t perw = 50176 + 2 * 50176 + 65536;  // x,q,k + vT = 216064 B
  size_t avail = (ws_size > off + 65536) ? ws_size - off - 65536 : 0;
  int CH = (int)(avail / perw);
  if (CH > 4096) CH = 4096;
  if (CH < 1) CH = 1;

  bf16* x_ws = (bf16*)(ws + off); off += (size_t)CH * 50176;
  bf16* q_ws = (bf16*)(ws + off); off += (size_t)CH * 50176;
  bf16* k_ws = (bf16*)(ws + off); off += (size_t)CH * 50176;
  bf16* vT_ws = (bf16*)(ws + off); off += (size_t)CH * 65536;

  cvt_w_kernel<<<256, 256, 0, stream>>>(Wk, Wq, Wv, Wp, (bf16*)wbf);
  prep_rpbL<<<64, 256, 0, stream>>>(btab, rpbL);
  prep_maskL<<<4096, 256, 0, stream>>>(mask, maskL);

  const float qscale = 0.17677669529663687f;  // 1/sqrt(32)
  for (int wstart = 0; wstart < 4096; wstart += CH) {
    const int nwin = (4096 - wstart < CH) ? (4096 - wstart) : CH;
    const int M = nwin * 49;
    const int gy = (M + 127) / 128;
    gemm_kqv<<<6 * gy, 512, 0, stream>>>(lf + (size_t)wstart * 25088,
                                         gfx + (size_t)wstart * 25088, wbf,
                                         bk, bq, bv, qscale, k_ws, q_ws,
                                         vT_ws, M);
    attn_win2<<<dim3(nwin, 4), 256, 0, stream>>>(q_ws, k_ws, vT_ws, rpbL,
                                                 maskL, x_ws, wstart);
    gemm_p<<<2 * gy, 512, 0, stream>>>((const short*)x_ws, wbf + 3 * 262144,
                                       bp, out + (size_t)wstart * 25088, M);
  }
}

// Round 15
// 1157.151 us; speedup vs baseline: 1.1415x; 1.0032x over previous
//
#include <hip/hip_runtime.h>
#include <hip/hip_bf16.h>

typedef __hip_bfloat16 bf16;
typedef __attribute__((ext_vector_type(4))) float f32x4;
typedef __attribute__((ext_vector_type(8))) short short8;
typedef __attribute__((ext_vector_type(4))) short short4v;

#define NEGBIG (-3.0e38f)

__device__ __forceinline__ unsigned short f2b(float x) {
  union { float f; unsigned int u; } v; v.f = x;
  unsigned int r = v.u + 0x7fffu + ((v.u >> 16) & 1u);
  return (unsigned short)(r >> 16);
}

__device__ __forceinline__ void gl16(const void* g, void* l) {
  __builtin_amdgcn_global_load_lds(
      (const __attribute__((address_space(1))) unsigned int*)g,
      (__attribute__((address_space(3))) unsigned int*)l, 16, 0, 0);
}

// bijective XCD-grouping swizzle (m204): contiguous tile range per XCD
__device__ __forceinline__ int xcd_swz(int orig, int nwg) {
  const int q = nwg >> 3, r = nwg & 7;
  const int xcd = orig & 7;
  const int base = (xcd < r) ? xcd * (q + 1) : r * (q + 1) + (xcd - r) * q;
  return base + (orig >> 3);
}

// ---------------- weight f32 -> bf16 (row-major) ----------------
__global__ __launch_bounds__(256) void cvt_w_kernel(
    const float* __restrict__ a, const float* __restrict__ b,
    const float* __restrict__ c, const float* __restrict__ d,
    bf16* __restrict__ dst) {
  const int t = blockIdx.x * 256 + threadIdx.x;
  const float* srcs[4] = {a, b, c, d};
#pragma unroll
  for (int w = 0; w < 4; ++w) {
    const f32x4 v = *(const f32x4*)(srcs[w] + (size_t)t * 4);
    short4v o;
    o[0] = (short)f2b(v[0]); o[1] = (short)f2b(v[1]);
    o[2] = (short)f2b(v[2]); o[3] = (short)f2b(v[3]);
    *(short4v*)((short*)dst + (size_t)w * 262144 + (size_t)t * 4) = o;
  }
}

// ---- bias table -> per-(head, frag-element) layout, pads = NEGBIG ----
__global__ __launch_bounds__(256) void prep_rpbL(const float* __restrict__ btab,
                                                 float* __restrict__ rpbL) {
  const int g = blockIdx.x * 256 + threadIdx.x;
  const int lane = g & 63, mn = (g >> 6) & 15, h = g >> 10;
  const int m = mn >> 2, n = mn & 3, l15 = lane & 15, lg = lane >> 4;
  const int cc = n * 16 + l15;
  const int aj = cc / 7, bj = cc % 7;
  f32x4 o;
#pragma unroll
  for (int reg = 0; reg < 4; ++reg) {
    const int i = m * 16 + lg * 4 + reg;
    if (i < 49 && cc < 49) {
      const int t = (i / 7 - aj + 6) * 13 + (i % 7 - bj + 6);
      o[reg] = btab[t * 16 + h];
    } else {
      o[reg] = NEGBIG;
    }
  }
  ((f32x4*)rpbL)[g] = o;
}

// ---- mask -> per-(window, frag-element) layout, pads = 0 ----
__global__ __launch_bounds__(256) void prep_maskL(const float* __restrict__ mask,
                                                  float* __restrict__ maskL) {
  const int g = blockIdx.x * 256 + threadIdx.x;
  const int lane = g & 63, mn = (g >> 6) & 15, wm = g >> 10;
  const int m = mn >> 2, n = mn & 3, l15 = lane & 15, lg = lane >> 4;
  const int cc = n * 16 + l15;
  f32x4 o;
#pragma unroll
  for (int reg = 0; reg < 4; ++reg) {
    const int i = m * 16 + lg * 4 + reg;
    o[reg] = (i < 49 && cc < 49) ? mask[(size_t)wm * 2401 + i * 49 + cc] : 0.f;
  }
  ((f32x4*)maskL)[g] = o;
}

// ---------------- fused KQV GEMM, m97 geometry, f32-A in-LDS convert --------
// grid 6*gy, XCD-swizzled; bn%6: cls = bn>>1 (0=K,1=Q,2=V^T), bnl = bn&1.
// BM=128 (tokens), BN=256 (channels), BK=64, 8 waves. LDS (80KB, 2 blk/CU):
//   Af32 [0,32K): 128x64 f32, linear (gl16 direct from f32 activations)
//   Abf  [32K,48K): 128x64 bf16, R8 layout/swizzle (written by convert phase)
//   Bs   [48K,80K): 256x64 bf16, R8 layout/swizzle (gl16 from bf16 weights)
// Per K-step (2 barriers): issue A gl16 (4), issue B gl16 (4),
// s_waitcnt vmcnt(4) -> thread's OWN A slots landed (stage & convert use the
// same tid-slot map, so no cross-thread dep) -> in-LDS convert (cvt_pk RNE)
// -> __syncthreads (drains B + Abf writes) -> R8-identical ds_read + 32 MFMA
// -> __syncthreads. Convert is hidden under B's memory latency.
__global__ __launch_bounds__(512, 4) void gemm_kqv(
    const float* __restrict__ lf, const float* __restrict__ gfx,
    const short* __restrict__ wbf, const float* __restrict__ bk,
    const float* __restrict__ bq, const float* __restrict__ bv, float qscale,
    bf16* __restrict__ k_ws, bf16* __restrict__ q_ws, bf16* __restrict__ vT_ws,
    int M) {
  __shared__ char lds[81920];
  char* Af32 = lds;           // 32 KB
  char* Abf = lds + 32768;    // 16 KB
  char* Bs = lds + 49152;     // 32 KB
  const int nwg = gridDim.x;
  const int t0 = xcd_swz(blockIdx.x, nwg);
  const int bn = t0 % 6, bm = t0 / 6;
  const int cls = bn >> 1, bnl = bn & 1;
  const int tid = threadIdx.x, lane = tid & 63, wid = tid >> 6;
  const int l15 = lane & 15, lg = lane >> 4;
  const bool swap = (cls == 2);
  // normal: wr (2) x wc (4); swap: cm (4, channels) x ct (2, tokens)
  const int wr = swap ? (wid & 3) : (wid >> 2);
  const int wc = swap ? (wid >> 2) : (wid & 3);
  const float* Af = (cls == 1) ? gfx : lf;
  const char* Bb = (const char*)(wbf + (size_t)cls * 262144);

  f32x4 acc[4][4];
#pragma unroll
  for (int m = 0; m < 4; ++m)
#pragma unroll
    for (int n = 0; n < 4; ++n) acc[m][n] = (f32x4){0.f, 0.f, 0.f, 0.f};

  const char* fam = swap ? Bs : Abf;  // A-operand source (m-axis rows)
  const char* fbm = swap ? Abf : Bs;  // B-operand source (n-axis rows)

  // convert-phase constants (thread t covers f32 slot col tid&15 of rows
  // crow0 + {0,32,64,96} == exactly the slots its own gl16s staged)
  const int crow0 = tid >> 4;
  const int ccol = tid & 15;
  const int c4 = ccol >> 1, hh8 = (ccol & 1) * 8;

  for (int kt = 0; kt < 8; ++kt) {
    const int k0 = kt * 64;
    // ---- issue A f32 (4 gl16, linear dest, self-slots) FIRST ----
#pragma unroll
    for (int i = 0; i < 4; ++i) {
      const int s = tid + 512 * i;
      const int row = s >> 4, col = s & 15;
      int gr = bm * 128 + row;
      if (gr >= M) gr = M - 1;  // clamp: keep source reads in-bounds
      gl16((const char*)Af + (size_t)gr * 2048 + k0 * 4 + col * 16,
           Af32 + s * 16);
    }
    // ---- issue B bf16 (4 gl16, R8 swizzled source) SECOND ----
#pragma unroll
    for (int i = 0; i < 4; ++i) {
      const int s = tid + 512 * i;
      const int row = s >> 3;
      const int sc = (s & 7) ^ (row & 7);
      gl16(Bb + (size_t)(bnl * 256 + row) * 1024 + k0 * 2 + sc * 16,
           Bs + s * 16);
    }
    // wait only for this thread's A loads (B's 4 stay in flight)
    asm volatile("s_waitcnt vmcnt(4)" ::: "memory");
    __builtin_amdgcn_sched_barrier(0);

    // ---- convert own slots: Af32 -> Abf (R8 layout) ----
#pragma unroll
    for (int j = 0; j < 4; ++j) {
      const int rj = crow0 + 32 * j;
      const f32x4 v = *(const f32x4*)(Af32 + (tid + 512 * j) * 16);
      unsigned int w0, w1;
      asm("v_cvt_pk_bf16_f32 %0, %1, %2" : "=v"(w0) : "v"(v[0]), "v"(v[1]));
      asm("v_cvt_pk_bf16_f32 %0, %1, %2" : "=v"(w1) : "v"(v[2]), "v"(v[3]));
      *(unsigned long long*)(Abf + rj * 128 + (((c4 ^ (rj & 7)) << 4) | hh8)) =
          ((unsigned long long)w1 << 32) | w0;
    }
    __syncthreads();  // drains B gl16s (vmcnt 0) + Abf ds_writes (lgkm 0)

    // ---- compute: R8-identical read path + MFMA ----
#pragma unroll
    for (int s = 0; s < 2; ++s) {
      short8 af[4], bfr[4];
#pragma unroll
      for (int m = 0; m < 4; ++m) {
        const int r = wr * 64 + m * 16 + l15;
        af[m] = *(const short8*)(fam + r * 128 +
                                 (((s * 4 + lg) ^ (r & 7)) << 4));
      }
#pragma unroll
      for (int n = 0; n < 4; ++n) {
        const int r = wc * 64 + n * 16 + l15;
        bfr[n] = *(const short8*)(fbm + r * 128 +
                                  (((s * 4 + lg) ^ (r & 7)) << 4));
      }
#pragma unroll
      for (int m = 0; m < 4; ++m)
#pragma unroll
        for (int n = 0; n < 4; ++n)
          acc[m][n] = __builtin_amdgcn_mfma_f32_16x16x32_bf16(
              af[m], bfr[n], acc[m][n], 0, 0, 0);
    }
    __syncthreads();  // all reads done before next stage overwrites
  }

  if (cls == 2) {  // V^T: m-axis = channels (256), n-axis = tokens (128)
#pragma unroll
    for (int m = 0; m < 4; ++m) {
#pragma unroll
      for (int n = 0; n < 4; ++n) {
        const int tok = bm * 128 + wc * 64 + n * 16 + l15;
        if (tok < M) {
          const int w = tok / 49, nt = tok - w * 49;
#pragma unroll
          for (int reg = 0; reg < 4; ++reg) {
            const int ch = bnl * 256 + wr * 64 + m * 16 + lg * 4 + reg;
            const float v = acc[m][n][reg] + bv[ch];
            const int hh = ch >> 5, dd = ch & 31;
            vT_ws[(((size_t)w * 16 + hh) * 32 + dd) * 64 + nt] =
                __float2bfloat16(v);
          }
        }
      }
    }
  } else {
    const float* bb = (cls == 0) ? bk : bq;
    bf16* dp = (cls == 0) ? k_ws : q_ws;
    const float sc = (cls == 0) ? 1.0f : qscale;
#pragma unroll
    for (int m = 0; m < 4; ++m) {
#pragma unroll
      for (int n = 0; n < 4; ++n) {
        const int c = bnl * 256 + wc * 64 + n * 16 + l15;
        const float bvv = bb[c];
        const int hh = c >> 5, dd = c & 31;
#pragma unroll
        for (int reg = 0; reg < 4; ++reg) {
          const int r = bm * 128 + wr * 64 + m * 16 + lg * 4 + reg;
          if (r < M) {
            const int w = r / 49, nt = r - w * 49;
            dp[(((size_t)w * 16 + hh) * 49 + nt) * 32 + dd] =
                __float2bfloat16((acc[m][n][reg] + bvv) * sc);
          }
        }
      }
    }
  }
}

// ------- m97-geometry staging (proj): A 128x64, B 256x64 bf16, swizzled -----
__device__ __forceinline__ void stage_m97(const char* Ab, const char* Bb,
                                          char* As, char* Bs, int arow0,
                                          int brow0, int k0) {
  const int tid = threadIdx.x;  // 512 threads
#pragma unroll
  for (int i = 0; i < 2; ++i) {
    const int s = tid + 512 * i;  // A: 1024 slots of 16B
    const int row = s >> 3;
    const int sc = (s & 7) ^ (row & 7);
    gl16(Ab + (size_t)(arow0 + row) * 1024 + k0 * 2 + sc * 16, As + s * 16);
  }
#pragma unroll
  for (int i = 0; i < 4; ++i) {
    const int s = tid + 512 * i;  // B: 2048 slots of 16B
    const int row = s >> 3;
    const int sc = (s & 7) ^ (row & 7);
    gl16(Bb + (size_t)(brow0 + row) * 1024 + k0 * 2 + sc * 16, Bs + s * 16);
  }
}

// ---------------- proj GEMM, m97 geometry: f32 out [r][512] -----------------
__global__ __launch_bounds__(512, 4) void gemm_p(const short* __restrict__ Abf,
                                                 const short* __restrict__ Bbf,
                                                 const float* __restrict__ bias,
                                                 float* __restrict__ dst,
                                                 int M) {
  __shared__ char lds[49152];
  char* As = lds;
  char* Bs = lds + 16384;
  const int nwg = gridDim.x;
  const int t0 = xcd_swz(blockIdx.x, nwg);
  const int bnl = t0 & 1, bm = t0 >> 1;
  const int tid = threadIdx.x, lane = tid & 63, wid = tid >> 6;
  const int wr = wid >> 2, wc = wid & 3, l15 = lane & 15, lg = lane >> 4;

  f32x4 acc[4][4];
#pragma unroll
  for (int m = 0; m < 4; ++m)
#pragma unroll
    for (int n = 0; n < 4; ++n) acc[m][n] = (f32x4){0.f, 0.f, 0.f, 0.f};

  for (int kt = 0; kt < 8; ++kt) {
    stage_m97((const char*)Abf, (const char*)Bbf, As, Bs, bm * 128, bnl * 256,
              kt * 64);
    __syncthreads();
#pragma unroll
    for (int s = 0; s < 2; ++s) {
      short8 af[4], bfr[4];
#pragma unroll
      for (int m = 0; m < 4; ++m) {
        const int r = wr * 64 + m * 16 + l15;
        af[m] = *(const short8*)(As + r * 128 +
                                 (((s * 4 + lg) ^ (r & 7)) << 4));
      }
#pragma unroll
      for (int n = 0; n < 4; ++n) {
        const int r = wc * 64 + n * 16 + l15;
        bfr[n] = *(const short8*)(Bs + r * 128 +
                                  (((s * 4 + lg) ^ (r & 7)) << 4));
      }
#pragma unroll
      for (int m = 0; m < 4; ++m)
#pragma unroll
        for (int n = 0; n < 4; ++n)
          acc[m][n] = __builtin_amdgcn_mfma_f32_16x16x32_bf16(
              af[m], bfr[n], acc[m][n], 0, 0, 0);
    }
    __syncthreads();
  }

#pragma unroll
  for (int m = 0; m < 4; ++m) {
#pragma unroll
    for (int n = 0; n < 4; ++n) {
      const int c = bnl * 256 + wc * 64 + n * 16 + l15;
      const float bvv = bias[c];
#pragma unroll
      for (int reg = 0; reg < 4; ++reg) {
        const int r = bm * 128 + wr * 64 + m * 16 + lg * 4 + reg;
        if (r < M) dst[(size_t)r * 512 + c] = acc[m][n][reg] + bvv;
      }
    }
  }
}

// ---------------- windowed attention: 1 head per wave, no barriers ---------
__global__ __launch_bounds__(256) void attn_win2(
    const bf16* __restrict__ q_ws, const bf16* __restrict__ k_ws,
    const bf16* __restrict__ vT_ws, const float* __restrict__ rpbL,
    const float* __restrict__ maskL, bf16* __restrict__ x_ws, int wstart) {
  __shared__ short sP[4][4096];
  const int tid = threadIdx.x, lane = tid & 63, wid = tid >> 6;
  const int l15 = lane & 15, lg = lane >> 4;
  const int wl = blockIdx.x;
  const int h = blockIdx.y * 4 + wid;
  const int wg = wstart + wl;
  char* Pl = (char*)sP[wid];
  const size_t base = ((size_t)wl * 16 + h) * 1568;
  const short8 z8 = (short8){0, 0, 0, 0, 0, 0, 0, 0};

  short8 qf[4], kf[4];
#pragma unroll
  for (int m = 0; m < 4; ++m) {
    const int r = m * 16 + l15;
    qf[m] = (r < 49) ? *(const short8*)(q_ws + base + r * 32 + lg * 8) : z8;
    kf[m] = (r < 49) ? *(const short8*)(k_ws + base + r * 32 + lg * 8) : z8;
  }
  f32x4 lc[4][4];
#pragma unroll
  for (int m = 0; m < 4; ++m)
#pragma unroll
    for (int n = 0; n < 4; ++n)
      lc[m][n] = __builtin_amdgcn_mfma_f32_16x16x32_bf16(
          qf[m], kf[n], (f32x4){0.f, 0.f, 0.f, 0.f}, 0, 0, 0);

  const f32x4* rbp = (const f32x4*)rpbL + (size_t)h * 1024 + lane;
  const f32x4* mkp = (const f32x4*)maskL + (size_t)(wg & 1023) * 1024 + lane;
#pragma unroll
  for (int m = 0; m < 4; ++m)
#pragma unroll
    for (int n = 0; n < 4; ++n) {
      const int mn = m * 4 + n;
      lc[m][n] += rbp[mn * 64] + mkp[mn * 64];
    }

#pragma unroll
  for (int m = 0; m < 4; ++m) {
#pragma unroll
    for (int reg = 0; reg < 4; ++reg) {
      float vmax = fmaxf(fmaxf(lc[m][0][reg], lc[m][1][reg]),
                         fmaxf(lc[m][2][reg], lc[m][3][reg]));
#pragma unroll
      for (int off = 1; off < 16; off <<= 1)
        vmax = fmaxf(vmax, __shfl_xor(vmax, off, 64));
      float e[4], ssum = 0.f;
#pragma unroll
      for (int n = 0; n < 4; ++n) {
        e[n] = __expf(lc[m][n][reg] - vmax);
        ssum += e[n];
      }
#pragma unroll
      for (int off = 1; off < 16; off <<= 1) ssum += __shfl_xor(ssum, off, 64);
      const float inv = __builtin_amdgcn_rcpf(ssum);
      const int i = m * 16 + lg * 4 + reg;
#pragma unroll
      for (int n = 0; n < 4; ++n) {
        const int cc = n * 16 + l15;
        *(unsigned short*)(Pl + i * 128 + ((2 * cc) ^ ((i & 7) << 4))) =
            f2b(e[n] * inv);
      }
    }
  }

  f32x4 xacc[4][2];
#pragma unroll
  for (int m = 0; m < 4; ++m)
#pragma unroll
    for (int n = 0; n < 2; ++n) xacc[m][n] = (f32x4){0.f, 0.f, 0.f, 0.f};
  const size_t vbase = ((size_t)wl * 16 + h) * 2048;
#pragma unroll
  for (int s = 0; s < 2; ++s) {
    short8 pf[4], vf[2];
#pragma unroll
    for (int m = 0; m < 4; ++m) {
      const int i = m * 16 + l15;
      pf[m] = *(const short8*)(Pl + i * 128 +
                               ((s * 64 + lg * 16) ^ ((i & 7) << 4)));
    }
#pragma unroll
    for (int n = 0; n < 2; ++n) {
      const int dd = n * 16 + l15;
      short8 vv = *(const short8*)(vT_ws + vbase + dd * 64 + s * 32 + lg * 8);
      if (s == 1) {
        if (lg == 3) vv = z8;
        else if (lg == 2) {
          vv[1] = 0; vv[2] = 0; vv[3] = 0; vv[4] = 0;
          vv[5] = 0; vv[6] = 0; vv[7] = 0;
        }
      }
      vf[n] = vv;
    }
#pragma unroll
    for (int m = 0; m < 4; ++m)
#pragma unroll
      for (int n = 0; n < 2; ++n)
        xacc[m][n] = __builtin_amdgcn_mfma_f32_16x16x32_bf16(
            pf[m], vf[n], xacc[m][n], 0, 0, 0);
  }

#pragma unroll
  for (int m = 0; m < 4; ++m)
#pragma unroll
    for (int n = 0; n < 2; ++n)
#pragma unroll
      for (int reg = 0; reg < 4; ++reg) {
        const int i = m * 16 + lg * 4 + reg;
        const int dd = n * 16 + l15;
        *(unsigned short*)(Pl + i * 80 + ((2 * dd) ^ ((i & 3) << 4))) =
            f2b(xacc[m][n][reg]);
      }
#pragma unroll
  for (int g = 0; g < 4; ++g) {
    const int row = g * 16 + (lane >> 2);
    if (row < 49) {
      const short8 xv = *(const short8*)(
          Pl + row * 80 + (((lane & 3) * 16) ^ ((row & 3) << 4)));
      *(short8*)(x_ws + ((size_t)wl * 49 + row) * 512 + h * 32 +
                 (lane & 3) * 8) = xv;
    }
  }
}

extern "C" void kernel_launch(void* const* d_in, const int* in_sizes, int n_in,
                              void* d_out, int out_size, void* d_ws,
                              size_t ws_size, hipStream_t stream) {
  const float* lf   = (const float*)d_in[0];
  const float* gfx  = (const float*)d_in[1];
  const float* mask = (const float*)d_in[2];
  const float* btab = (const float*)d_in[3];
  const float* Wk = (const float*)d_in[4];  const float* bk = (const float*)d_in[5];
  const float* Wq = (const float*)d_in[6];  const float* bq = (const float*)d_in[7];
  const float* Wv = (const float*)d_in[8];  const float* bv = (const float*)d_in[9];
  const float* Wp = (const float*)d_in[10]; const float* bp = (const float*)d_in[11];
  float* out = (float*)d_out;

  char* ws = (char*)d_ws;
  short* wbf = (short*)ws;  // 4 x 512x512 bf16 = 2 MB
  size_t off = (size_t)4 * 262144 * 2;
  float* rpbL = (float*)(ws + off); off += (size_t)16 * 4096 * 4;     // 256 KB
  float* maskL = (float*)(ws + off); off += (size_t)1024 * 4096 * 4;  // 16 MB

  const size_t perw = 50176 + 2 * 50176 + 65536;  // x,q,k + vT = 216064 B
  size_t avail = (ws_size > off + 65536) ? ws_size - off - 65536 : 0;
  int CH = (int)(avail / perw);
  if (CH > 4096) CH = 4096;
  if (CH < 1) CH = 1;

  bf16* x_ws = (bf16*)(ws + off); off += (size_t)CH * 50176;
  bf16* q_ws = (bf16*)(ws + off); off += (size_t)CH * 50176;
  bf16* k_ws = (bf16*)(ws + off); off += (size_t)CH * 50176;
  bf16* vT_ws = (bf16*)(ws + off); off += (size_t)CH * 65536;

  cvt_w_kernel<<<256, 256, 0, stream>>>(Wk, Wq, Wv, Wp, (bf16*)wbf);
  prep_rpbL<<<64, 256, 0, stream>>>(btab, rpbL);
  prep_maskL<<<4096, 256, 0, stream>>>(mask, maskL);

  const float qscale = 0.17677669529663687f;  // 1/sqrt(32)
  for (int wstart = 0; wstart < 4096; wstart += CH) {
    const int nwin = (4096 - wstart < CH) ? (4096 - wstart) : CH;
    const int M = nwin * 49;
    const int gy = (M + 127) / 128;
    gemm_kqv<<<6 * gy, 512, 0, stream>>>(lf + (size_t)wstart * 25088,
                                         gfx + (size_t)wstart * 25088, wbf,
                                         bk, bq, bv, qscale, k_ws, q_ws,
                                         vT_ws, M);
    attn_win2<<<dim3(nwin, 4), 256, 0, stream>>>(q_ws, k_ws, vT_ws, rpbL,
                                                 maskL, x_ws, wstart);
    gemm_p<<<2 * gy, 512, 0, stream>>>((const short*)x_ws, wbf + 3 * 262144,
                                       bp, out + (size_t)wstart * 25088, M);
  }
}

// Round 17
// 1145.838 us; speedup vs baseline: 1.1528x; 1.0099x over previous
//
#include <hip/hip_runtime.h>
#include <hip/hip_bf16.h>

typedef __hip_bfloat16 bf16;
typedef __attribute__((ext_vector_type(4))) float f32x4;
typedef __attribute__((ext_vector_type(8))) short short8;
typedef __attribute__((ext_vector_type(4))) short short4v;

#define NEGBIG (-3.0e38f)

__device__ __forceinline__ unsigned short f2b(float x) {
  union { float f; unsigned int u; } v; v.f = x;
  unsigned int r = v.u + 0x7fffu + ((v.u >> 16) & 1u);
  return (unsigned short)(r >> 16);
}

__device__ __forceinline__ void gl16(const void* g, void* l) {
  __builtin_amdgcn_global_load_lds(
      (const __attribute__((address_space(1))) unsigned int*)g,
      (__attribute__((address_space(3))) unsigned int*)l, 16, 0, 0);
}

// bijective XCD-grouping swizzle (m204): contiguous tile range per XCD
__device__ __forceinline__ int xcd_swz(int orig, int nwg) {
  const int q = nwg >> 3, r = nwg & 7;
  const int xcd = orig & 7;
  const int base = (xcd < r) ? xcd * (q + 1) : r * (q + 1) + (xcd - r) * q;
  return base + (orig >> 3);
}

// ---------------- weight f32 -> bf16 (row-major) ----------------
__global__ __launch_bounds__(256) void cvt_w_kernel(
    const float* __restrict__ a, const float* __restrict__ b,
    const float* __restrict__ c, const float* __restrict__ d,
    bf16* __restrict__ dst) {
  const int t = blockIdx.x * 256 + threadIdx.x;
  const float* srcs[4] = {a, b, c, d};
#pragma unroll
  for (int w = 0; w < 4; ++w) {
    const f32x4 v = *(const f32x4*)(srcs[w] + (size_t)t * 4);
    short4v o;
    o[0] = (short)f2b(v[0]); o[1] = (short)f2b(v[1]);
    o[2] = (short)f2b(v[2]); o[3] = (short)f2b(v[3]);
    *(short4v*)((short*)dst + (size_t)w * 262144 + (size_t)t * 4) = o;
  }
}

// ---- bias table -> per-(head, frag-element) layout, pads = NEGBIG ----
__global__ __launch_bounds__(256) void prep_rpbL(const float* __restrict__ btab,
                                                 float* __restrict__ rpbL) {
  const int g = blockIdx.x * 256 + threadIdx.x;
  const int lane = g & 63, mn = (g >> 6) & 15, h = g >> 10;
  const int m = mn >> 2, n = mn & 3, l15 = lane & 15, lg = lane >> 4;
  const int cc = n * 16 + l15;
  const int aj = cc / 7, bj = cc % 7;
  f32x4 o;
#pragma unroll
  for (int reg = 0; reg < 4; ++reg) {
    const int i = m * 16 + lg * 4 + reg;
    if (i < 49 && cc < 49) {
      const int t = (i / 7 - aj + 6) * 13 + (i % 7 - bj + 6);
      o[reg] = btab[t * 16 + h];
    } else {
      o[reg] = NEGBIG;
    }
  }
  ((f32x4*)rpbL)[g] = o;
}

// ---- mask -> per-(window, frag-element) layout, pads = 0 ----
__global__ __launch_bounds__(256) void prep_maskL(const float* __restrict__ mask,
                                                  float* __restrict__ maskL) {
  const int g = blockIdx.x * 256 + threadIdx.x;
  const int lane = g & 63, mn = (g >> 6) & 15, wm = g >> 10;
  const int m = mn >> 2, n = mn & 3, l15 = lane & 15, lg = lane >> 4;
  const int cc = n * 16 + l15;
  f32x4 o;
#pragma unroll
  for (int reg = 0; reg < 4; ++reg) {
    const int i = m * 16 + lg * 4 + reg;
    o[reg] = (i < 49 && cc < 49) ? mask[(size_t)wm * 2401 + i * 49 + cc] : 0.f;
  }
  ((f32x4*)maskL)[g] = o;
}

// ---------------- fused KQV GEMM, m97 geometry, f32-A in-LDS convert --------
// grid 6*gy, XCD-swizzled; bn%6: cls = bn>>1 (0=K,1=Q,2=V^T), bnl = bn&1.
// BM=128 (tokens), BN=256 (channels), BK=64, 8 waves. LDS (80KB, 2 blk/CU):
//   Af32 [0,32K): 128x64 f32, linear (gl16 from f32 activations)
//   Abf  [32K,48K): 128x64 bf16, R8 layout/swizzle (convert phase)
//   Bs   [48K,80K): 256x64 bf16, R8 layout/swizzle (gl16 from bf16 weights)
// Pipelined K-step, __syncthreads-only fences (R16's raw-barrier raced):
//   issue B(kt); vmcnt(4) [retires A(kt); no-op in steady state];
//   convert(kt); __syncthreads [B + Abf resident; Af32 now dead];
//   issue A(kt+1) prefetch into dead Af32; 32-MFMA compute covers its
//   latency; __syncthreads [drains the (mostly complete) prefetch + orders
//   LDS reads vs next writers].
__global__ __launch_bounds__(512, 4) void gemm_kqv(
    const float* __restrict__ lf, const float* __restrict__ gfx,
    const short* __restrict__ wbf, const float* __restrict__ bk,
    const float* __restrict__ bq, const float* __restrict__ bv, float qscale,
    bf16* __restrict__ k_ws, bf16* __restrict__ q_ws, bf16* __restrict__ vT_ws,
    int M) {
  __shared__ char lds[81920];
  char* Af32 = lds;           // 32 KB
  char* Abf = lds + 32768;    // 16 KB
  char* Bs = lds + 49152;     // 32 KB
  const int nwg = gridDim.x;
  const int t0 = xcd_swz(blockIdx.x, nwg);
  const int bn = t0 % 6, bm = t0 / 6;
  const int cls = bn >> 1, bnl = bn & 1;
  const int tid = threadIdx.x, lane = tid & 63, wid = tid >> 6;
  const int l15 = lane & 15, lg = lane >> 4;
  const bool swap = (cls == 2);
  // normal: wr (2) x wc (4); swap: cm (4, channels) x ct (2, tokens)
  const int wr = swap ? (wid & 3) : (wid >> 2);
  const int wc = swap ? (wid >> 2) : (wid & 3);
  const float* Af = (cls == 1) ? gfx : lf;
  const char* Bb = (const char*)(wbf + (size_t)cls * 262144);

  f32x4 acc[4][4];
#pragma unroll
  for (int m = 0; m < 4; ++m)
#pragma unroll
    for (int n = 0; n < 4; ++n) acc[m][n] = (f32x4){0.f, 0.f, 0.f, 0.f};

  const char* fam = swap ? Bs : Abf;  // A-operand source (m-axis rows)
  const char* fbm = swap ? Abf : Bs;  // B-operand source (n-axis rows)

  // convert-phase constants (thread t covers f32 slot col tid&15 of rows
  // crow0 + {0,32,64,96} == exactly the slots its own gl16s staged)
  const int crow0 = tid >> 4;
  const int ccol = tid & 15;
  const int c4 = ccol >> 1, hh8 = (ccol & 1) * 8;

#define ISSUE_A(k0)                                                        \
  do {                                                                     \
    _Pragma("unroll") for (int i = 0; i < 4; ++i) {                        \
      const int s = tid + 512 * i;                                         \
      const int row = s >> 4, col = s & 15;                                \
      int gr = bm * 128 + row;                                             \
      if (gr >= M) gr = M - 1; /* clamp: in-bounds source */               \
      gl16((const char*)Af + (size_t)gr * 2048 + (k0) * 4 + col * 16,      \
           Af32 + s * 16);                                                 \
    }                                                                      \
  } while (0)

  // prologue: A(0) in flight
  ISSUE_A(0);

  for (int kt = 0; kt < 8; ++kt) {
    const int k0 = kt * 64;
    // ---- issue B bf16 (4 gl16, R8 swizzled source) ----
#pragma unroll
    for (int i = 0; i < 4; ++i) {
      const int s = tid + 512 * i;
      const int row = s >> 3;
      const int sc = (s & 7) ^ (row & 7);
      gl16(Bb + (size_t)(bnl * 256 + row) * 1024 + k0 * 2 + sc * 16,
           Bs + s * 16);
    }
    // retire this thread's A loads (no-op in steady state: the previous
    // end-of-step __syncthreads already drained them); B's stay in flight
    asm volatile("s_waitcnt vmcnt(4)" ::: "memory");
    __builtin_amdgcn_sched_barrier(0);

    // ---- convert own slots: Af32 -> Abf (R8 layout) ----
#pragma unroll
    for (int j = 0; j < 4; ++j) {
      const int rj = crow0 + 32 * j;
      const f32x4 v = *(const f32x4*)(Af32 + (tid + 512 * j) * 16);
      unsigned int w0, w1;
      asm("v_cvt_pk_bf16_f32 %0, %1, %2" : "=v"(w0) : "v"(v[0]), "v"(v[1]));
      asm("v_cvt_pk_bf16_f32 %0, %1, %2" : "=v"(w1) : "v"(v[2]), "v"(v[3]));
      *(unsigned long long*)(Abf + rj * 128 + (((c4 ^ (rj & 7)) << 4) | hh8)) =
          ((unsigned long long)w1 << 32) | w0;
    }
    __syncthreads();  // drains B gl16s + Abf ds_writes; Af32 now DEAD

    // ---- prefetch A(kt+1) into dead Af32; MFMA cluster covers latency ----
    if (kt < 7) ISSUE_A(k0 + 64);

    // ---- compute: R8-identical read path + MFMA ----
#pragma unroll
    for (int s = 0; s < 2; ++s) {
      short8 af[4], bfr[4];
#pragma unroll
      for (int m = 0; m < 4; ++m) {
        const int r = wr * 64 + m * 16 + l15;
        af[m] = *(const short8*)(fam + r * 128 +
                                 (((s * 4 + lg) ^ (r & 7)) << 4));
      }
#pragma unroll
      for (int n = 0; n < 4; ++n) {
        const int r = wc * 64 + n * 16 + l15;
        bfr[n] = *(const short8*)(fbm + r * 128 +
                                  (((s * 4 + lg) ^ (r & 7)) << 4));
      }
#pragma unroll
      for (int m = 0; m < 4; ++m)
#pragma unroll
        for (int n = 0; n < 4; ++n)
          acc[m][n] = __builtin_amdgcn_mfma_f32_16x16x32_bf16(
              af[m], bfr[n], acc[m][n], 0, 0, 0);
    }
    __syncthreads();  // full fence: drains prefetch (mostly complete) and
                      // orders all LDS reads vs next iteration's writers
  }
#undef ISSUE_A

  if (cls == 2) {  // V^T: m-axis = channels (256), n-axis = tokens (128)
#pragma unroll
    for (int m = 0; m < 4; ++m) {
#pragma unroll
      for (int n = 0; n < 4; ++n) {
        const int tok = bm * 128 + wc * 64 + n * 16 + l15;
        if (tok < M) {
          const int w = tok / 49, nt = tok - w * 49;
#pragma unroll
          for (int reg = 0; reg < 4; ++reg) {
            const int ch = bnl * 256 + wr * 64 + m * 16 + lg * 4 + reg;
            const float v = acc[m][n][reg] + bv[ch];
            const int hh = ch >> 5, dd = ch & 31;
            vT_ws[(((size_t)w * 16 + hh) * 32 + dd) * 64 + nt] =
                __float2bfloat16(v);
          }
        }
      }
    }
  } else {
    const float* bb = (cls == 0) ? bk : bq;
    bf16* dp = (cls == 0) ? k_ws : q_ws;
    const float sc = (cls == 0) ? 1.0f : qscale;
#pragma unroll
    for (int m = 0; m < 4; ++m) {
#pragma unroll
      for (int n = 0; n < 4; ++n) {
        const int c = bnl * 256 + wc * 64 + n * 16 + l15;
        const float bvv = bb[c];
        const int hh = c >> 5, dd = c & 31;
#pragma unroll
        for (int reg = 0; reg < 4; ++reg) {
          const int r = bm * 128 + wr * 64 + m * 16 + lg * 4 + reg;
          if (r < M) {
            const int w = r / 49, nt = r - w * 49;
            dp[(((size_t)w * 16 + hh) * 49 + nt) * 32 + dd] =
                __float2bfloat16((acc[m][n][reg] + bvv) * sc);
          }
        }
      }
    }
  }
}

// ------- m97-geometry staging (proj): A 128x64, B 256x64 bf16, swizzled -----
__device__ __forceinline__ void stage_m97(const char* Ab, const char* Bb,
                                          char* As, char* Bs, int arow0,
                                          int brow0, int k0) {
  const int tid = threadIdx.x;  // 512 threads
#pragma unroll
  for (int i = 0; i < 2; ++i) {
    const int s = tid + 512 * i;  // A: 1024 slots of 16B
    const int row = s >> 3;
    const int sc = (s & 7) ^ (row & 7);
    gl16(Ab + (size_t)(arow0 + row) * 1024 + k0 * 2 + sc * 16, As + s * 16);
  }
#pragma unroll
  for (int i = 0; i < 4; ++i) {
    const int s = tid + 512 * i;  // B: 2048 slots of 16B
    const int row = s >> 3;
    const int sc = (s & 7) ^ (row & 7);
    gl16(Bb + (size_t)(brow0 + row) * 1024 + k0 * 2 + sc * 16, Bs + s * 16);
  }
}

// ---------------- proj GEMM, m97 geometry: f32 out [r][512] -----------------
__global__ __launch_bounds__(512, 4) void gemm_p(const short* __restrict__ Abf,
                                                 const short* __restrict__ Bbf,
                                                 const float* __restrict__ bias,
                                                 float* __restrict__ dst,
                                                 int M) {
  __shared__ char lds[49152];
  char* As = lds;
  char* Bs = lds + 16384;
  const int nwg = gridDim.x;
  const int t0 = xcd_swz(blockIdx.x, nwg);
  const int bnl = t0 & 1, bm = t0 >> 1;
  const int tid = threadIdx.x, lane = tid & 63, wid = tid >> 6;
  const int wr = wid >> 2, wc = wid & 3, l15 = lane & 15, lg = lane >> 4;

  f32x4 acc[4][4];
#pragma unroll
  for (int m = 0; m < 4; ++m)
#pragma unroll
    for (int n = 0; n < 4; ++n) acc[m][n] = (f32x4){0.f, 0.f, 0.f, 0.f};

  for (int kt = 0; kt < 8; ++kt) {
    stage_m97((const char*)Abf, (const char*)Bbf, As, Bs, bm * 128, bnl * 256,
              kt * 64);
    __syncthreads();
#pragma unroll
    for (int s = 0; s < 2; ++s) {
      short8 af[4], bfr[4];
#pragma unroll
      for (int m = 0; m < 4; ++m) {
        const int r = wr * 64 + m * 16 + l15;
        af[m] = *(const short8*)(As + r * 128 +
                                 (((s * 4 + lg) ^ (r & 7)) << 4));
      }
#pragma unroll
      for (int n = 0; n < 4; ++n) {
        const int r = wc * 64 + n * 16 + l15;
        bfr[n] = *(const short8*)(Bs + r * 128 +
                                  (((s * 4 + lg) ^ (r & 7)) << 4));
      }
#pragma unroll
      for (int m = 0; m < 4; ++m)
#pragma unroll
        for (int n = 0; n < 4; ++n)
          acc[m][n] = __builtin_amdgcn_mfma_f32_16x16x32_bf16(
              af[m], bfr[n], acc[m][n], 0, 0, 0);
    }
    __syncthreads();
  }

#pragma unroll
  for (int m = 0; m < 4; ++m) {
#pragma unroll
    for (int n = 0; n < 4; ++n) {
      const int c = bnl * 256 + wc * 64 + n * 16 + l15;
      const float bvv = bias[c];
#pragma unroll
      for (int reg = 0; reg < 4; ++reg) {
        const int r = bm * 128 + wr * 64 + m * 16 + lg * 4 + reg;
        if (r < M) dst[(size_t)r * 512 + c] = acc[m][n][reg] + bvv;
      }
    }
  }
}

// ---------------- windowed attention: 1 head per wave, no barriers ---------
__global__ __launch_bounds__(256) void attn_win2(
    const bf16* __restrict__ q_ws, const bf16* __restrict__ k_ws,
    const bf16* __restrict__ vT_ws, const float* __restrict__ rpbL,
    const float* __restrict__ maskL, bf16* __restrict__ x_ws, int wstart) {
  __shared__ short sP[4][4096];
  const int tid = threadIdx.x, lane = tid & 63, wid = tid >> 6;
  const int l15 = lane & 15, lg = lane >> 4;
  const int wl = blockIdx.x;
  const int h = blockIdx.y * 4 + wid;
  const int wg = wstart + wl;
  char* Pl = (char*)sP[wid];
  const size_t base = ((size_t)wl * 16 + h) * 1568;
  const short8 z8 = (short8){0, 0, 0, 0, 0, 0, 0, 0};

  short8 qf[4], kf[4];
#pragma unroll
  for (int m = 0; m < 4; ++m) {
    const int r = m * 16 + l15;
    qf[m] = (r < 49) ? *(const short8*)(q_ws + base + r * 32 + lg * 8) : z8;
    kf[m] = (r < 49) ? *(const short8*)(k_ws + base + r * 32 + lg * 8) : z8;
  }
  f32x4 lc[4][4];
  __builtin_amdgcn_s_setprio(1);
#pragma unroll
  for (int m = 0; m < 4; ++m)
#pragma unroll
    for (int n = 0; n < 4; ++n)
      lc[m][n] = __builtin_amdgcn_mfma_f32_16x16x32_bf16(
          qf[m], kf[n], (f32x4){0.f, 0.f, 0.f, 0.f}, 0, 0, 0);
  __builtin_amdgcn_s_setprio(0);

  const f32x4* rbp = (const f32x4*)rpbL + (size_t)h * 1024 + lane;
  const f32x4* mkp = (const f32x4*)maskL + (size_t)(wg & 1023) * 1024 + lane;
#pragma unroll
  for (int m = 0; m < 4; ++m)
#pragma unroll
    for (int n = 0; n < 4; ++n) {
      const int mn = m * 4 + n;
      lc[m][n] += rbp[mn * 64] + mkp[mn * 64];
    }

#pragma unroll
  for (int m = 0; m < 4; ++m) {
#pragma unroll
    for (int reg = 0; reg < 4; ++reg) {
      float vmax = fmaxf(fmaxf(lc[m][0][reg], lc[m][1][reg]),
                         fmaxf(lc[m][2][reg], lc[m][3][reg]));
#pragma unroll
      for (int off = 1; off < 16; off <<= 1)
        vmax = fmaxf(vmax, __shfl_xor(vmax, off, 64));
      float e[4], ssum = 0.f;
#pragma unroll
      for (int n = 0; n < 4; ++n) {
        e[n] = __expf(lc[m][n][reg] - vmax);
        ssum += e[n];
      }
#pragma unroll
      for (int off = 1; off < 16; off <<= 1) ssum += __shfl_xor(ssum, off, 64);
      const float inv = __builtin_amdgcn_rcpf(ssum);
      const int i = m * 16 + lg * 4 + reg;
#pragma unroll
      for (int n = 0; n < 4; ++n) {
        const int cc = n * 16 + l15;
        *(unsigned short*)(Pl + i * 128 + ((2 * cc) ^ ((i & 7) << 4))) =
            f2b(e[n] * inv);
      }
    }
  }

  f32x4 xacc[4][2];
#pragma unroll
  for (int m = 0; m < 4; ++m)
#pragma unroll
    for (int n = 0; n < 2; ++n) xacc[m][n] = (f32x4){0.f, 0.f, 0.f, 0.f};
  const size_t vbase = ((size_t)wl * 16 + h) * 2048;
#pragma unroll
  for (int s = 0; s < 2; ++s) {
    short8 pf[4], vf[2];
#pragma unroll
    for (int m = 0; m < 4; ++m) {
      const int i = m * 16 + l15;
      pf[m] = *(const short8*)(Pl + i * 128 +
                               ((s * 64 + lg * 16) ^ ((i & 7) << 4)));
    }
#pragma unroll
    for (int n = 0; n < 2; ++n) {
      const int dd = n * 16 + l15;
      short8 vv = *(const short8*)(vT_ws + vbase + dd * 64 + s * 32 + lg * 8);
      if (s == 1) {
        if (lg == 3) vv = z8;
        else if (lg == 2) {
          vv[1] = 0; vv[2] = 0; vv[3] = 0; vv[4] = 0;
          vv[5] = 0; vv[6] = 0; vv[7] = 0;
        }
      }
      vf[n] = vv;
    }
    __builtin_amdgcn_s_setprio(1);
#pragma unroll
    for (int m = 0; m < 4; ++m)
#pragma unroll
      for (int n = 0; n < 2; ++n)
        xacc[m][n] = __builtin_amdgcn_mfma_f32_16x16x32_bf16(
            pf[m], vf[n], xacc[m][n], 0, 0, 0);
    __builtin_amdgcn_s_setprio(0);
  }

#pragma unroll
  for (int m = 0; m < 4; ++m)
#pragma unroll
    for (int n = 0; n < 2; ++n)
#pragma unroll
      for (int reg = 0; reg < 4; ++reg) {
        const int i = m * 16 + lg * 4 + reg;
        const int dd = n * 16 + l15;
        *(unsigned short*)(Pl + i * 80 + ((2 * dd) ^ ((i & 3) << 4))) =
            f2b(xacc[m][n][reg]);
      }
#pragma unroll
  for (int g = 0; g < 4; ++g) {
    const int row = g * 16 + (lane >> 2);
    if (row < 49) {
      const short8 xv = *(const short8*)(
          Pl + row * 80 + (((lane & 3) * 16) ^ ((row & 3) << 4)));
      *(short8*)(x_ws + ((size_t)wl * 49 + row) * 512 + h * 32 +
                 (lane & 3) * 8) = xv;
    }
  }
}

extern "C" void kernel_launch(void* const* d_in, const int* in_sizes, int n_in,
                              void* d_out, int out_size, void* d_ws,
                              size_t ws_size, hipStream_t stream) {
  const float* lf   = (const float*)d_in[0];
  const float* gfx  = (const float*)d_in[1];
  const float* mask = (const float*)d_in[2];
  const float* btab = (const float*)d_in[3];
  const float* Wk = (const float*)d_in[4];  const float* bk = (const float*)d_in[5];
  const float* Wq = (const float*)d_in[6];  const float* bq = (const float*)d_in[7];
  const float* Wv = (const float*)d_in[8];  const float* bv = (const float*)d_in[9];
  const float* Wp = (const float*)d_in[10]; const float* bp = (const float*)d_in[11];
  float* out = (float*)d_out;

  char* ws = (char*)d_ws;
  short* wbf = (short*)ws;  // 4 x 512x512 bf16 = 2 MB
  size_t off = (size_t)4 * 262144 * 2;
  float* rpbL = (float*)(ws + off); off += (size_t)16 * 4096 * 4;     // 256 KB
  float* maskL = (float*)(ws + off); off += (size_t)1024 * 4096 * 4;  // 16 MB

  const size_t perw = 50176 + 2 * 50176 + 65536;  // x,q,k + vT = 216064 B
  size_t avail = (ws_size > off + 65536) ? ws_size - off - 65536 : 0;
  int CH = (int)(avail / perw);
  if (CH > 4096) CH = 4096;
  if (CH < 1) CH = 1;

  bf16* x_ws = (bf16*)(ws + off); off += (size_t)CH * 50176;
  bf16* q_ws = (bf16*)(ws + off); off += (size_t)CH * 50176;
  bf16* k_ws = (bf16*)(ws + off); off += (size_t)CH * 50176;
  bf16* vT_ws = (bf16*)(ws + off); off += (size_t)CH * 65536;

  cvt_w_kernel<<<256, 256, 0, stream>>>(Wk, Wq, Wv, Wp, (bf16*)wbf);
  prep_rpbL<<<64, 256, 0, stream>>>(btab, rpbL);
  prep_maskL<<<4096, 256, 0, stream>>>(mask, maskL);

  const float qscale = 0.17677669529663687f;  // 1/sqrt(32)
  for (int wstart = 0; wstart < 4096; wstart += CH) {
    const int nwin = (4096 - wstart < CH) ? (4096 - wstart) : CH;
    const int M = nwin * 49;
    const int gy = (M + 127) / 128;
    gemm_kqv<<<6 * gy, 512, 0, stream>>>(lf + (size_t)wstart * 25088,
                                         gfx + (size_t)wstart * 25088, wbf,
                                         bk, bq, bv, qscale, k_ws, q_ws,
                                         vT_ws, M);
    attn_win2<<<dim3(nwin, 4), 256, 0, stream>>>(q_ws, k_ws, vT_ws, rpbL,
                                                 maskL, x_ws, wstart);
    gemm_p<<<2 * gy, 512, 0, stream>>>((const short*)x_ws, wbf + 3 * 262144,
                                       bp, out + (size_t)wstart * 25088, M);
  }
}